// Round 1
// baseline (473.377 us; speedup 1.0000x reference)
//
#include <hip/hip_runtime.h>
#include <hip/hip_bf16.h>
#include <stdint.h>

// Transformer layer: S=2048, B=2, D=1024, H=16, DH=64, FF=4096. fp32 in/out.
// Strategy: fp32 LN/softmax/accum, bf16 MFMA (16x16x32) for all GEMMs.

#define S_LEN 2048
#define BATCH 2
#define DMODEL 1024
#define NHEAD 16
#define DHEAD 64
#define FFDIM 4096
#define MROWS (S_LEN * BATCH)  // 4096 rows, row index = s*B + b

typedef unsigned short u16;
typedef __attribute__((ext_vector_type(8))) __bf16 bf16x8;
typedef __attribute__((ext_vector_type(4))) float f32x4;
typedef __attribute__((ext_vector_type(4))) u16 u16x4;

__device__ inline u16 f2bf(float f) {
  union { float f; unsigned u; } v; v.f = f;
  unsigned r = v.u + 0x7fffu + ((v.u >> 16) & 1u);  // round-to-nearest-even
  return (u16)(r >> 16);
}

__device__ inline f32x4 mfma16(bf16x8 a, bf16x8 b, f32x4 c) {
  return __builtin_amdgcn_mfma_f32_16x16x32_bf16(a, b, c, 0, 0, 0);
}

// async global->LDS, 16B per lane. LDS dest must be wave-uniform base; HW adds lane*16.
__device__ inline void gload_lds16(const u16* g, u16* l) {
  __builtin_amdgcn_global_load_lds(
      (const __attribute__((address_space(1))) unsigned int*)g,
      (__attribute__((address_space(3))) unsigned int*)l, 16, 0, 0);
}

// ---------------- LayerNorm: fp32 in -> bf16 out ----------------
__global__ __launch_bounds__(256) void ln_kernel(const float* __restrict__ x,
                                                 const float* __restrict__ gam,
                                                 const float* __restrict__ bet,
                                                 u16* __restrict__ out) {
  int row = blockIdx.x;
  int tid = threadIdx.x;
  const float4* xr = (const float4*)(x + (size_t)row * DMODEL);
  float4 v = xr[tid];
  float s = v.x + v.y + v.z + v.w;
  float ss = v.x * v.x + v.y * v.y + v.z * v.z + v.w * v.w;
#pragma unroll
  for (int m = 1; m < 64; m <<= 1) {
    s += __shfl_xor(s, m);
    ss += __shfl_xor(ss, m);
  }
  __shared__ float red[8];
  int w = tid >> 6, lane = tid & 63;
  if (lane == 0) { red[w] = s; red[4 + w] = ss; }
  __syncthreads();
  s = red[0] + red[1] + red[2] + red[3];
  ss = red[4] + red[5] + red[6] + red[7];
  float mu = s * (1.f / DMODEL);
  float var = ss * (1.f / DMODEL) - mu * mu;
  float rstd = rsqrtf(var + 1e-5f);
  float4 gv = ((const float4*)gam)[tid];
  float4 bv = ((const float4*)bet)[tid];
  u16x4 o;
  o.x = f2bf((v.x - mu) * rstd * gv.x + bv.x);
  o.y = f2bf((v.y - mu) * rstd * gv.y + bv.y);
  o.z = f2bf((v.z - mu) * rstd * gv.z + bv.z);
  o.w = f2bf((v.w - mu) * rstd * gv.w + bv.w);
  *(u16x4*)(out + (size_t)row * DMODEL + tid * 4) = o;
}

// ---------------- fp32 [R][C] -> bf16 [C][R] ----------------
__global__ __launch_bounds__(256) void transpose_cast(const float* __restrict__ in,
                                                      u16* __restrict__ out, int R, int C) {
  __shared__ u16 tile[32][33];
  int c0 = blockIdx.x * 32, r0 = blockIdx.y * 32;
  int tx = threadIdx.x & 31, grp = threadIdx.x >> 5;
#pragma unroll
  for (int i = 0; i < 4; i++) {
    int r = grp * 4 + i;
    tile[r][tx] = f2bf(in[(size_t)(r0 + r) * C + c0 + tx]);
  }
  __syncthreads();
#pragma unroll
  for (int i = 0; i < 4; i++) {
    int rr = grp * 4 + i;
    out[(size_t)(c0 + rr) * R + r0 + tx] = tile[tx][rr];
  }
}

// ---------------- V slice of qkv -> Vt[bh][dh][s] ----------------
__global__ __launch_bounds__(256) void transpose_v(const u16* __restrict__ qkv,
                                                   u16* __restrict__ vt) {
  __shared__ u16 tile[32][33];
  int bh = blockIdx.z;
  int b = bh >> 4;
  int s0 = blockIdx.x * 32, d0 = blockIdx.y * 32;
  int h = bh & 15;
  int tx = threadIdx.x & 31, grp = threadIdx.x >> 5;
#pragma unroll
  for (int i = 0; i < 4; i++) {
    int sl = grp * 4 + i;
    tile[sl][tx] = qkv[(size_t)((s0 + sl) * BATCH + b) * 3072 + 2048 + h * DHEAD + d0 + tx];
  }
  __syncthreads();
#pragma unroll
  for (int i = 0; i < 4; i++) {
    int dl = grp * 4 + i;
    vt[((size_t)bh * DHEAD + d0 + dl) * S_LEN + s0 + tx] = tile[tx][dl];
  }
}

// ---------------- GEMM: C[M][N] = A[M][K](bf16) @ Bt[N][K](bf16)^T ----------------
// MODE 0: bf16 out.  MODE 1: fp32 out = acc + res.
// MODE 2: bf16 out = relu(acc + bias).  MODE 3: fp32 out = acc + bias + res.
template <int MODE>
__global__ __launch_bounds__(256) void gemm_bt(const u16* __restrict__ A,
                                               const u16* __restrict__ Bt, void* __restrict__ Cout,
                                               const float* __restrict__ bias,
                                               const float* __restrict__ res, int M, int N, int K) {
  __shared__ __align__(16) u16 As[128 * 32];
  __shared__ __align__(16) u16 Bs[128 * 32];
  int bm0 = blockIdx.y * 128, bn0 = blockIdx.x * 128;
  int tid = threadIdx.x, w = tid >> 6, lane = tid & 63;
  int g = lane >> 4, l15 = lane & 15;
  int wm = (w >> 1) * 64, wn = (w & 1) * 64;
  f32x4 acc[4][4];
#pragma unroll
  for (int i = 0; i < 4; i++)
#pragma unroll
    for (int j = 0; j < 4; j++) {
      f32x4 z = {0.f, 0.f, 0.f, 0.f};
      acc[i][j] = z;
    }
  for (int k0 = 0; k0 < K; k0 += 32) {
#pragma unroll
    for (int rd = 0; rd < 2; rd++) {
      int fb = (rd * 4 + w) * 512;       // wave-uniform LDS element base
      int lf = fb + lane * 8;            // this lane's element slot
      int r = lf >> 5, c = lf & 31;
      gload_lds16(A + (size_t)(bm0 + r) * K + k0 + c, &As[fb]);
      gload_lds16(Bt + (size_t)(bn0 + r) * K + k0 + c, &Bs[fb]);
    }
    __syncthreads();  // drains vmcnt before barrier
    bf16x8 af[4], bfr[4];
#pragma unroll
    for (int i = 0; i < 4; i++)
      af[i] = *(const bf16x8*)&As[(wm + i * 16 + l15) * 32 + g * 8];
#pragma unroll
    for (int i = 0; i < 4; i++)
      bfr[i] = *(const bf16x8*)&Bs[(wn + i * 16 + l15) * 32 + g * 8];
#pragma unroll
    for (int i = 0; i < 4; i++)
#pragma unroll
      for (int j = 0; j < 4; j++) acc[i][j] = mfma16(af[i], bfr[j], acc[i][j]);
    __syncthreads();
  }
  // epilogue: D layout col = lane&15, row = 4*(lane>>4) + r
#pragma unroll
  for (int i = 0; i < 4; i++)
#pragma unroll
    for (int j = 0; j < 4; j++) {
      int col = bn0 + wn + j * 16 + l15;
      float bval = (MODE == 2 || MODE == 3) ? bias[col] : 0.f;
#pragma unroll
      for (int r = 0; r < 4; r++) {
        int row = bm0 + wm + i * 16 + g * 4 + r;
        size_t idx = (size_t)row * N + col;
        float vacc = acc[i][j][r] + bval;
        if (MODE == 0)
          ((u16*)Cout)[idx] = f2bf(vacc);
        else if (MODE == 1)
          ((float*)Cout)[idx] = vacc + res[idx];
        else if (MODE == 2)
          ((u16*)Cout)[idx] = f2bf(fmaxf(vacc, 0.f));
        else
          ((float*)Cout)[idx] = vacc + res[idx];
      }
    }
}

// ---------------- flash attention ----------------
// grid (S/64, B*H), 256 thr = 4 waves; wave w owns 16 q rows.
// qkv: [4096][3072] bf16 (q|k|v). vt: [bh][dh][s]. ctx out: [4096][1024] bf16.
__global__ __launch_bounds__(256) void attn_kernel(const u16* __restrict__ qkv,
                                                   const u16* __restrict__ vt,
                                                   u16* __restrict__ ctx) {
  int bh = blockIdx.y;
  int b = bh >> 4, h = bh & 15;
  int tid = threadIdx.x, w = tid >> 6, lane = tid & 63;
  int g = lane >> 4, l15 = lane & 15;
  int q0 = blockIdx.x * 64 + w * 16;
  const size_t ldq = 3072;

  const u16* qp = qkv + ((size_t)(q0 + l15) * BATCH + b) * ldq + h * DHEAD;
  bf16x8 qf0 = *(const bf16x8*)(qp + g * 8);
  bf16x8 qf1 = *(const bf16x8*)(qp + 32 + g * 8);

  f32x4 acc[4];
#pragma unroll
  for (int n = 0; n < 4; n++) {
    f32x4 z = {0.f, 0.f, 0.f, 0.f};
    acc[n] = z;
  }
  float mrun[4], lrun[4];
#pragma unroll
  for (int r = 0; r < 4; r++) { mrun[r] = -1e30f; lrun[r] = 0.f; }

  __shared__ __align__(16) u16 p_lds[4][16][32];

  for (int t0 = 0; t0 < S_LEN; t0 += 32) {
    f32x4 sc[2];
#pragma unroll
    for (int tt = 0; tt < 2; tt++) {
      const u16* kp = qkv + ((size_t)(t0 + tt * 16 + l15) * BATCH + b) * ldq + 1024 + h * DHEAD;
      bf16x8 kf0 = *(const bf16x8*)(kp + g * 8);
      bf16x8 kf1 = *(const bf16x8*)(kp + 32 + g * 8);
      f32x4 z = {0.f, 0.f, 0.f, 0.f};
      z = mfma16(qf0, kf0, z);
      z = mfma16(qf1, kf1, z);
      sc[tt] = z * 0.125f;  // 1/sqrt(64)
    }
    // scores: lane holds q = g*4+r (rows), t = tile t0+16*tt+l15 (cols)
    float pm[4];
#pragma unroll
    for (int r = 0; r < 4; r++) pm[r] = fmaxf(sc[0][r], sc[1][r]);
#pragma unroll
    for (int mk = 1; mk < 16; mk <<= 1)
#pragma unroll
      for (int r = 0; r < 4; r++) pm[r] = fmaxf(pm[r], __shfl_xor(pm[r], mk));
    float alpha[4], p0[4], p1[4], psum[4];
#pragma unroll
    for (int r = 0; r < 4; r++) {
      float mn = fmaxf(mrun[r], pm[r]);
      alpha[r] = __expf(mrun[r] - mn);
      mrun[r] = mn;
      p0[r] = __expf(sc[0][r] - mn);
      p1[r] = __expf(sc[1][r] - mn);
      psum[r] = p0[r] + p1[r];
    }
#pragma unroll
    for (int mk = 1; mk < 16; mk <<= 1)
#pragma unroll
      for (int r = 0; r < 4; r++) psum[r] += __shfl_xor(psum[r], mk);
#pragma unroll
    for (int r = 0; r < 4; r++) lrun[r] = lrun[r] * alpha[r] + psum[r];
#pragma unroll
    for (int n = 0; n < 4; n++)
#pragma unroll
      for (int r = 0; r < 4; r++) acc[n][r] *= alpha[r];
    // P -> LDS (transpose across lanes into A-frag layout)
#pragma unroll
    for (int r = 0; r < 4; r++) {
      p_lds[w][g * 4 + r][l15] = f2bf(p0[r]);
      p_lds[w][g * 4 + r][16 + l15] = f2bf(p1[r]);
    }
    __syncthreads();
    bf16x8 pf = *(const bf16x8*)&p_lds[w][l15][g * 8];
#pragma unroll
    for (int n = 0; n < 4; n++) {
      const u16* vp = vt + ((size_t)bh * DHEAD + n * 16 + l15) * S_LEN + t0 + g * 8;
      bf16x8 vf = *(const bf16x8*)vp;
      acc[n] = mfma16(pf, vf, acc[n]);
    }
    __syncthreads();
  }
#pragma unroll
  for (int r = 0; r < 4; r++) lrun[r] = 1.f / lrun[r];
#pragma unroll
  for (int n = 0; n < 4; n++)
#pragma unroll
    for (int r = 0; r < 4; r++) {
      int s = q0 + g * 4 + r;
      ctx[((size_t)s * BATCH + b) * DMODEL + h * DHEAD + n * 16 + l15] = f2bf(acc[n][r] * lrun[r]);
    }
}

extern "C" void kernel_launch(void* const* d_in, const int* in_sizes, int n_in, void* d_out,
                              int out_size, void* d_ws, size_t ws_size, hipStream_t stream) {
  (void)in_sizes; (void)n_in; (void)out_size; (void)ws_size;
  const float* x    = (const float*)d_in[0];
  const float* wq   = (const float*)d_in[1];
  const float* wk   = (const float*)d_in[2];
  const float* wv   = (const float*)d_in[3];
  const float* wo   = (const float*)d_in[4];
  const float* ln1g = (const float*)d_in[5];
  const float* ln1b = (const float*)d_in[6];
  const float* ln2g = (const float*)d_in[7];
  const float* ln2b = (const float*)d_in[8];
  const float* w1   = (const float*)d_in[9];
  const float* b1   = (const float*)d_in[10];
  const float* w2   = (const float*)d_in[11];
  const float* b2   = (const float*)d_in[12];

  char* ws = (char*)d_ws;
  size_t off = 0;
  auto alloc = [&](size_t bytes) {
    void* p = ws + off;
    off += (bytes + 255) & ~(size_t)255;
    return p;
  };
  u16* yb    = (u16*)alloc((size_t)MROWS * DMODEL * 2);
  u16* wqkvt = (u16*)alloc((size_t)3072 * 1024 * 2);
  u16* wot   = (u16*)alloc((size_t)1024 * 1024 * 2);
  u16* w1t   = (u16*)alloc((size_t)4096 * 1024 * 2);
  u16* w2t   = (u16*)alloc((size_t)1024 * 4096 * 2);
  u16* qkvb  = (u16*)alloc((size_t)MROWS * 3072 * 2);
  u16* vtb   = (u16*)alloc((size_t)BATCH * NHEAD * DHEAD * S_LEN * 2);
  u16* ctxb  = (u16*)alloc((size_t)MROWS * DMODEL * 2);
  float* x1  = (float*)alloc((size_t)MROWS * DMODEL * 4);
  u16* zb    = (u16*)alloc((size_t)MROWS * DMODEL * 2);
  u16* hb    = (u16*)alloc((size_t)MROWS * FFDIM * 2);

  // sublayer 0
  ln_kernel<<<MROWS, 256, 0, stream>>>(x, ln1g, ln1b, yb);
  transpose_cast<<<dim3(32, 32), 256, 0, stream>>>(wq, wqkvt, 1024, 1024);
  transpose_cast<<<dim3(32, 32), 256, 0, stream>>>(wk, wqkvt + 1024 * 1024, 1024, 1024);
  transpose_cast<<<dim3(32, 32), 256, 0, stream>>>(wv, wqkvt + 2 * 1024 * 1024, 1024, 1024);
  transpose_cast<<<dim3(32, 32), 256, 0, stream>>>(wo, wot, 1024, 1024);
  transpose_cast<<<dim3(128, 32), 256, 0, stream>>>(w1, w1t, 1024, 4096);
  transpose_cast<<<dim3(32, 128), 256, 0, stream>>>(w2, w2t, 4096, 1024);

  gemm_bt<0><<<dim3(3072 / 128, 4096 / 128), 256, 0, stream>>>(yb, wqkvt, qkvb, nullptr, nullptr,
                                                               4096, 3072, 1024);
  transpose_v<<<dim3(64, 2, 32), 256, 0, stream>>>(qkvb, vtb);
  attn_kernel<<<dim3(32, 32), 256, 0, stream>>>(qkvb, vtb, ctxb);
  gemm_bt<1><<<dim3(8, 32), 256, 0, stream>>>(ctxb, wot, x1, nullptr, x, 4096, 1024, 1024);

  // sublayer 1
  ln_kernel<<<MROWS, 256, 0, stream>>>(x1, ln2g, ln2b, zb);
  gemm_bt<2><<<dim3(32, 32), 256, 0, stream>>>(zb, w1t, hb, b1, nullptr, 4096, 4096, 1024);
  gemm_bt<3><<<dim3(8, 32), 256, 0, stream>>>(hb, w2t, d_out, b2, x1, 4096, 1024, 4096);
}

// Round 2
// 355.300 us; speedup vs baseline: 1.3323x; 1.3323x over previous
//
#include <hip/hip_runtime.h>
#include <hip/hip_bf16.h>
#include <stdint.h>

// Transformer layer: S=2048, B=2, D=1024, H=16, DH=64, FF=4096. fp32 in/out.
// Strategy: fp32 LN/softmax/accum, bf16 MFMA (16x16x32) for all GEMMs.

#define S_LEN 2048
#define BATCH 2
#define DMODEL 1024
#define NHEAD 16
#define DHEAD 64
#define FFDIM 4096
#define MROWS (S_LEN * BATCH)  // 4096 rows, row index = s*B + b

typedef unsigned short u16;
typedef __attribute__((ext_vector_type(8))) __bf16 bf16x8;
typedef __attribute__((ext_vector_type(4))) float f32x4;
typedef __attribute__((ext_vector_type(4))) u16 u16x4;

__device__ inline u16 f2bf(float f) {
  union { float f; unsigned u; } v; v.f = f;
  unsigned r = v.u + 0x7fffu + ((v.u >> 16) & 1u);  // round-to-nearest-even
  return (u16)(r >> 16);
}

__device__ inline f32x4 mfma16(bf16x8 a, bf16x8 b, f32x4 c) {
  return __builtin_amdgcn_mfma_f32_16x16x32_bf16(a, b, c, 0, 0, 0);
}

// async global->LDS, 16B per lane. LDS dest must be wave-uniform base; HW adds lane*16.
__device__ inline void gload_lds16(const u16* g, u16* l) {
  __builtin_amdgcn_global_load_lds(
      (const __attribute__((address_space(1))) unsigned int*)g,
      (__attribute__((address_space(3))) unsigned int*)l, 16, 0, 0);
}

// ---------------- LayerNorm: fp32 in -> bf16 out ----------------
__global__ __launch_bounds__(256) void ln_kernel(const float* __restrict__ x,
                                                 const float* __restrict__ gam,
                                                 const float* __restrict__ bet,
                                                 u16* __restrict__ out) {
  int row = blockIdx.x;
  int tid = threadIdx.x;
  const float4* xr = (const float4*)(x + (size_t)row * DMODEL);
  float4 v = xr[tid];
  float s = v.x + v.y + v.z + v.w;
  float ss = v.x * v.x + v.y * v.y + v.z * v.z + v.w * v.w;
#pragma unroll
  for (int m = 1; m < 64; m <<= 1) {
    s += __shfl_xor(s, m);
    ss += __shfl_xor(ss, m);
  }
  __shared__ float red[8];
  int w = tid >> 6, lane = tid & 63;
  if (lane == 0) { red[w] = s; red[4 + w] = ss; }
  __syncthreads();
  s = red[0] + red[1] + red[2] + red[3];
  ss = red[4] + red[5] + red[6] + red[7];
  float mu = s * (1.f / DMODEL);
  float var = ss * (1.f / DMODEL) - mu * mu;
  float rstd = rsqrtf(var + 1e-5f);
  float4 gv = ((const float4*)gam)[tid];
  float4 bv = ((const float4*)bet)[tid];
  u16x4 o;
  o.x = f2bf((v.x - mu) * rstd * gv.x + bv.x);
  o.y = f2bf((v.y - mu) * rstd * gv.y + bv.y);
  o.z = f2bf((v.z - mu) * rstd * gv.z + bv.z);
  o.w = f2bf((v.w - mu) * rstd * gv.w + bv.w);
  *(u16x4*)(out + (size_t)row * DMODEL + tid * 4) = o;
}

// ---------------- fp32 [R][C] -> bf16 [C][R] ----------------
__global__ __launch_bounds__(256) void transpose_cast(const float* __restrict__ in,
                                                      u16* __restrict__ out, int R, int C) {
  __shared__ u16 tile[32][33];
  int c0 = blockIdx.x * 32, r0 = blockIdx.y * 32;
  int tx = threadIdx.x & 31, grp = threadIdx.x >> 5;
#pragma unroll
  for (int i = 0; i < 4; i++) {
    int r = grp * 4 + i;
    tile[r][tx] = f2bf(in[(size_t)(r0 + r) * C + c0 + tx]);
  }
  __syncthreads();
#pragma unroll
  for (int i = 0; i < 4; i++) {
    int rr = grp * 4 + i;
    out[(size_t)(c0 + rr) * R + r0 + tx] = tile[tx][rr];
  }
}

// ---------------- V slice of qkv -> Vt[bh][dh][s] ----------------
__global__ __launch_bounds__(256) void transpose_v(const u16* __restrict__ qkv,
                                                   u16* __restrict__ vt) {
  __shared__ u16 tile[32][33];
  int bh = blockIdx.z;
  int b = bh >> 4;
  int s0 = blockIdx.x * 32, d0 = blockIdx.y * 32;
  int h = bh & 15;
  int tx = threadIdx.x & 31, grp = threadIdx.x >> 5;
#pragma unroll
  for (int i = 0; i < 4; i++) {
    int sl = grp * 4 + i;
    tile[sl][tx] = qkv[(size_t)((s0 + sl) * BATCH + b) * 3072 + 2048 + h * DHEAD + d0 + tx];
  }
  __syncthreads();
#pragma unroll
  for (int i = 0; i < 4; i++) {
    int dl = grp * 4 + i;
    vt[((size_t)bh * DHEAD + d0 + dl) * S_LEN + s0 + tx] = tile[tx][dl];
  }
}

// ---------------- GEMM: C[M][N] = A[M][K](bf16) @ Bt[N][K](bf16)^T ----------------
// MODE 0: bf16 out.  MODE 1: fp32 out = acc + res.
// MODE 2: bf16 out = relu(acc + bias).  MODE 3: fp32 out = acc + bias + res.
template <int MODE>
__global__ __launch_bounds__(256) void gemm_bt(const u16* __restrict__ A,
                                               const u16* __restrict__ Bt, void* __restrict__ Cout,
                                               const float* __restrict__ bias,
                                               const float* __restrict__ res, int M, int N, int K) {
  __shared__ __align__(16) u16 As[128 * 32];
  __shared__ __align__(16) u16 Bs[128 * 32];
  int bm0 = blockIdx.y * 128, bn0 = blockIdx.x * 128;
  int tid = threadIdx.x, w = tid >> 6, lane = tid & 63;
  int g = lane >> 4, l15 = lane & 15;
  int wm = (w >> 1) * 64, wn = (w & 1) * 64;
  f32x4 acc[4][4];
#pragma unroll
  for (int i = 0; i < 4; i++)
#pragma unroll
    for (int j = 0; j < 4; j++) {
      f32x4 z = {0.f, 0.f, 0.f, 0.f};
      acc[i][j] = z;
    }
  for (int k0 = 0; k0 < K; k0 += 32) {
#pragma unroll
    for (int rd = 0; rd < 2; rd++) {
      int fb = (rd * 4 + w) * 512;       // wave-uniform LDS element base
      int lf = fb + lane * 8;            // this lane's element slot
      int r = lf >> 5, c = lf & 31;
      gload_lds16(A + (size_t)(bm0 + r) * K + k0 + c, &As[fb]);
      gload_lds16(Bt + (size_t)(bn0 + r) * K + k0 + c, &Bs[fb]);
    }
    __syncthreads();  // drains vmcnt before barrier
    bf16x8 af[4], bfr[4];
#pragma unroll
    for (int i = 0; i < 4; i++)
      af[i] = *(const bf16x8*)&As[(wm + i * 16 + l15) * 32 + g * 8];
#pragma unroll
    for (int i = 0; i < 4; i++)
      bfr[i] = *(const bf16x8*)&Bs[(wn + i * 16 + l15) * 32 + g * 8];
#pragma unroll
    for (int i = 0; i < 4; i++)
#pragma unroll
      for (int j = 0; j < 4; j++) acc[i][j] = mfma16(af[i], bfr[j], acc[i][j]);
    __syncthreads();
  }
  // epilogue: D layout col = lane&15, row = 4*(lane>>4) + r
#pragma unroll
  for (int i = 0; i < 4; i++)
#pragma unroll
    for (int j = 0; j < 4; j++) {
      int col = bn0 + wn + j * 16 + l15;
      float bval = (MODE == 2 || MODE == 3) ? bias[col] : 0.f;
#pragma unroll
      for (int r = 0; r < 4; r++) {
        int row = bm0 + wm + i * 16 + g * 4 + r;
        size_t idx = (size_t)row * N + col;
        float vacc = acc[i][j][r] + bval;
        if (MODE == 0)
          ((u16*)Cout)[idx] = f2bf(vacc);
        else if (MODE == 1)
          ((float*)Cout)[idx] = vacc + res[idx];
        else if (MODE == 2)
          ((u16*)Cout)[idx] = f2bf(fmaxf(vacc, 0.f));
        else
          ((float*)Cout)[idx] = vacc + res[idx];
      }
    }
}

// ---------------- flash attention v2: LDS-staged, double-buffered ----------------
// grid (S/128, B*H), 256 thr = 4 waves; wave w owns 32 q rows (2 x 16-row frag sets).
// KV tile = 64. K staged from qkv (k slice), V staged from vt[bh][dh][s].
// K/V LDS tiles are [row][8 chunks of 8 u16] with chunk ^= (row&7) XOR swizzle
// (linear gload_lds dest + pre-swizzled global source + swizzled ds_read: rule 21c).
__global__ __launch_bounds__(256) void attn_kernel(const u16* __restrict__ qkv,
                                                   const u16* __restrict__ vt,
                                                   u16* __restrict__ ctx) {
  int bh = blockIdx.y;
  int b = bh >> 4, h = bh & 15;
  int tid = threadIdx.x, w = tid >> 6, lane = tid & 63;
  int g = lane >> 4, l15 = lane & 15;
  int lr = lane >> 3, ch = lane & 7;
  int q0 = blockIdx.x * 128 + w * 32;

  __shared__ __align__(16) u16 ks[2][64 * 64];
  __shared__ __align__(16) u16 vs[2][64 * 64];
  __shared__ __align__(16) u16 ps[4][32 * 64];

  // Q fragments (one-time 16-line gathers)
  bf16x8 qf[2][2];
#pragma unroll
  for (int qs = 0; qs < 2; qs++) {
    const u16* qp = qkv + ((size_t)(q0 + qs * 16 + l15) * BATCH + b) * 3072 + h * DHEAD;
    qf[qs][0] = *(const bf16x8*)(qp + g * 8);
    qf[qs][1] = *(const bf16x8*)(qp + 32 + g * 8);
  }

  f32x4 acc[2][4];
#pragma unroll
  for (int qs = 0; qs < 2; qs++)
#pragma unroll
    for (int n = 0; n < 4; n++) {
      f32x4 z = {0.f, 0.f, 0.f, 0.f};
      acc[qs][n] = z;
    }
  float mrun[2][4], lrun[2][4];
#pragma unroll
  for (int qs = 0; qs < 2; qs++)
#pragma unroll
    for (int r = 0; r < 4; r++) { mrun[qs][r] = -1e30f; lrun[qs][r] = 0.f; }

  // stage KV tile t0 into buffer buf: each wave covers 16 rows (2 instrs of 8 rows)
  auto stage = [&](int t0, int buf) {
#pragma unroll
    for (int rd = 0; rd < 2; rd++) {
      int rb = w * 16 + rd * 8;
      int row = rb + lr;  // row & 7 == lr
      const u16* ksrc =
          qkv + ((size_t)(t0 + row) * BATCH + b) * 3072 + 1024 + h * DHEAD + (ch ^ lr) * 8;
      gload_lds16(ksrc, &ks[buf][rb * 64]);
      const u16* vsrc = vt + ((size_t)bh * DHEAD + row) * S_LEN + t0 + (ch ^ lr) * 8;
      gload_lds16(vsrc, &vs[buf][rb * 64]);
    }
  };

  stage(0, 0);
  __syncthreads();

  for (int it = 0; it < S_LEN / 64; ++it) {
    int cur = it & 1;
    if (it + 1 < S_LEN / 64) stage((it + 1) * 64, cur ^ 1);  // prefetch overlaps compute

    // ---- QK^T: sc[qs][tt][r] = S[q0 + qs*16 + 4g + r][t0 + tt*16 + l15] ----
    f32x4 sc[2][4];
#pragma unroll
    for (int tt = 0; tt < 4; tt++) {
      int row = tt * 16 + l15;
      bf16x8 kf0 = *(const bf16x8*)&ks[cur][row * 64 + ((g ^ (row & 7)) * 8)];
      bf16x8 kf1 = *(const bf16x8*)&ks[cur][row * 64 + (((4 + g) ^ (row & 7)) * 8)];
#pragma unroll
      for (int qs = 0; qs < 2; qs++) {
        f32x4 z = {0.f, 0.f, 0.f, 0.f};
        z = mfma16(qf[qs][0], kf0, z);
        z = mfma16(qf[qs][1], kf1, z);
        sc[qs][tt] = z * 0.125f;  // 1/sqrt(64)
      }
    }

    // ---- online softmax (per qs block; row = 4g+r, reduce over l15) ----
#pragma unroll
    for (int qs = 0; qs < 2; qs++) {
      float pm[4], alpha[4], psum[4], p[4][4];
#pragma unroll
      for (int r = 0; r < 4; r++)
        pm[r] = fmaxf(fmaxf(sc[qs][0][r], sc[qs][1][r]), fmaxf(sc[qs][2][r], sc[qs][3][r]));
#pragma unroll
      for (int mk = 1; mk < 16; mk <<= 1)
#pragma unroll
        for (int r = 0; r < 4; r++) pm[r] = fmaxf(pm[r], __shfl_xor(pm[r], mk));
#pragma unroll
      for (int r = 0; r < 4; r++) {
        float mn = fmaxf(mrun[qs][r], pm[r]);
        alpha[r] = __expf(mrun[qs][r] - mn);
        mrun[qs][r] = mn;
        psum[r] = 0.f;
#pragma unroll
        for (int tt = 0; tt < 4; tt++) {
          p[tt][r] = __expf(sc[qs][tt][r] - mn);
          psum[r] += p[tt][r];
        }
      }
#pragma unroll
      for (int mk = 1; mk < 16; mk <<= 1)
#pragma unroll
        for (int r = 0; r < 4; r++) psum[r] += __shfl_xor(psum[r], mk);
#pragma unroll
      for (int r = 0; r < 4; r++) lrun[qs][r] = lrun[qs][r] * alpha[r] + psum[r];
#pragma unroll
      for (int n = 0; n < 4; n++)
#pragma unroll
        for (int r = 0; r < 4; r++) acc[qs][n][r] *= alpha[r];
      // P -> wave-private LDS (swizzled), no barrier needed (same-wave lgkmcnt order)
#pragma unroll
      for (int tt = 0; tt < 4; tt++)
#pragma unroll
        for (int r = 0; r < 4; r++) {
          int q = qs * 16 + 4 * g + r;                      // q&7 == (4g+r)&7
          int chunk = (tt * 2 + (l15 >> 3)) ^ (q & 7);      // 16B chunk of t index
          ps[w][q * 64 + chunk * 8 + (l15 & 7)] = f2bf(p[tt][r]);
        }
    }

    // ---- PV: acc[qs][n] += P[q][t] * V[t][n*16+l15] ----
    bf16x8 pf[2][2];
#pragma unroll
    for (int qs = 0; qs < 2; qs++)
#pragma unroll
      for (int s2 = 0; s2 < 2; s2++) {
        int row = qs * 16 + l15;
        int chunk = (s2 * 4 + g) ^ (row & 7);
        pf[qs][s2] = *(const bf16x8*)&ps[w][row * 64 + chunk * 8];
      }
#pragma unroll
    for (int n = 0; n < 4; n++)
#pragma unroll
      for (int s2 = 0; s2 < 2; s2++) {
        int vrow = n * 16 + l15;
        int vchunk = (s2 * 4 + g) ^ (vrow & 7);
        bf16x8 vf = *(const bf16x8*)&vs[cur][vrow * 64 + vchunk * 8];
        acc[0][n] = mfma16(pf[0][s2], vf, acc[0][n]);
        acc[1][n] = mfma16(pf[1][s2], vf, acc[1][n]);
      }
    __syncthreads();  // drains vmcnt (prefetch landed) + orders K/V buffer reuse
  }

#pragma unroll
  for (int qs = 0; qs < 2; qs++)
#pragma unroll
    for (int r = 0; r < 4; r++) lrun[qs][r] = 1.f / lrun[qs][r];
#pragma unroll
  for (int qs = 0; qs < 2; qs++)
#pragma unroll
    for (int n = 0; n < 4; n++)
#pragma unroll
      for (int r = 0; r < 4; r++) {
        int srow = q0 + qs * 16 + 4 * g + r;
        ctx[((size_t)srow * BATCH + b) * DMODEL + h * DHEAD + n * 16 + l15] =
            f2bf(acc[qs][n][r] * lrun[qs][r]);
      }
}

extern "C" void kernel_launch(void* const* d_in, const int* in_sizes, int n_in, void* d_out,
                              int out_size, void* d_ws, size_t ws_size, hipStream_t stream) {
  (void)in_sizes; (void)n_in; (void)out_size; (void)ws_size;
  const float* x    = (const float*)d_in[0];
  const float* wq   = (const float*)d_in[1];
  const float* wk   = (const float*)d_in[2];
  const float* wv   = (const float*)d_in[3];
  const float* wo   = (const float*)d_in[4];
  const float* ln1g = (const float*)d_in[5];
  const float* ln1b = (const float*)d_in[6];
  const float* ln2g = (const float*)d_in[7];
  const float* ln2b = (const float*)d_in[8];
  const float* w1   = (const float*)d_in[9];
  const float* b1   = (const float*)d_in[10];
  const float* w2   = (const float*)d_in[11];
  const float* b2   = (const float*)d_in[12];

  char* ws = (char*)d_ws;
  size_t off = 0;
  auto alloc = [&](size_t bytes) {
    void* p = ws + off;
    off += (bytes + 255) & ~(size_t)255;
    return p;
  };
  u16* yb    = (u16*)alloc((size_t)MROWS * DMODEL * 2);
  u16* wqkvt = (u16*)alloc((size_t)3072 * 1024 * 2);
  u16* wot   = (u16*)alloc((size_t)1024 * 1024 * 2);
  u16* w1t   = (u16*)alloc((size_t)4096 * 1024 * 2);
  u16* w2t   = (u16*)alloc((size_t)1024 * 4096 * 2);
  u16* qkvb  = (u16*)alloc((size_t)MROWS * 3072 * 2);
  u16* vtb   = (u16*)alloc((size_t)BATCH * NHEAD * DHEAD * S_LEN * 2);
  u16* ctxb  = (u16*)alloc((size_t)MROWS * DMODEL * 2);
  float* x1  = (float*)alloc((size_t)MROWS * DMODEL * 4);
  u16* zb    = (u16*)alloc((size_t)MROWS * DMODEL * 2);
  u16* hb    = (u16*)alloc((size_t)MROWS * FFDIM * 2);

  // sublayer 0
  ln_kernel<<<MROWS, 256, 0, stream>>>(x, ln1g, ln1b, yb);
  transpose_cast<<<dim3(32, 32), 256, 0, stream>>>(wq, wqkvt, 1024, 1024);
  transpose_cast<<<dim3(32, 32), 256, 0, stream>>>(wk, wqkvt + 1024 * 1024, 1024, 1024);
  transpose_cast<<<dim3(32, 32), 256, 0, stream>>>(wv, wqkvt + 2 * 1024 * 1024, 1024, 1024);
  transpose_cast<<<dim3(32, 32), 256, 0, stream>>>(wo, wot, 1024, 1024);
  transpose_cast<<<dim3(128, 32), 256, 0, stream>>>(w1, w1t, 1024, 4096);
  transpose_cast<<<dim3(32, 128), 256, 0, stream>>>(w2, w2t, 4096, 1024);

  gemm_bt<0><<<dim3(3072 / 128, 4096 / 128), 256, 0, stream>>>(yb, wqkvt, qkvb, nullptr, nullptr,
                                                               4096, 3072, 1024);
  transpose_v<<<dim3(64, 2, 32), 256, 0, stream>>>(qkvb, vtb);
  attn_kernel<<<dim3(16, 32), 256, 0, stream>>>(qkvb, vtb, ctxb);
  gemm_bt<1><<<dim3(8, 32), 256, 0, stream>>>(ctxb, wot, x1, nullptr, x, 4096, 1024, 1024);

  // sublayer 1
  ln_kernel<<<MROWS, 256, 0, stream>>>(x1, ln2g, ln2b, zb);
  gemm_bt<2><<<dim3(32, 32), 256, 0, stream>>>(zb, w1t, hb, b1, nullptr, 4096, 4096, 1024);
  gemm_bt<3><<<dim3(8, 32), 256, 0, stream>>>(hb, w2t, d_out, b2, x1, 4096, 1024, 4096);
}

// Round 3
// 298.896 us; speedup vs baseline: 1.5838x; 1.1887x over previous
//
#include <hip/hip_runtime.h>
#include <hip/hip_bf16.h>
#include <stdint.h>

// Transformer layer: S=2048, B=2, D=1024, H=16, DH=64, FF=4096. fp32 in/out.
// Strategy: fp32 LN/softmax/accum, bf16 MFMA (16x16x32) for all GEMMs.

#define S_LEN 2048
#define BATCH 2
#define DMODEL 1024
#define NHEAD 16
#define DHEAD 64
#define FFDIM 4096
#define MROWS (S_LEN * BATCH)  // 4096 rows, row index = s*B + b

typedef unsigned short u16;
typedef __attribute__((ext_vector_type(8))) __bf16 bf16x8;
typedef __attribute__((ext_vector_type(4))) float f32x4;
typedef __attribute__((ext_vector_type(4))) u16 u16x4;

__device__ inline u16 f2bf(float f) {
  union { float f; unsigned u; } v; v.f = f;
  unsigned r = v.u + 0x7fffu + ((v.u >> 16) & 1u);  // round-to-nearest-even
  return (u16)(r >> 16);
}

__device__ inline f32x4 mfma16(bf16x8 a, bf16x8 b, f32x4 c) {
  return __builtin_amdgcn_mfma_f32_16x16x32_bf16(a, b, c, 0, 0, 0);
}

// async global->LDS, 16B per lane. LDS dest must be wave-uniform base; HW adds lane*16.
__device__ inline void gload_lds16(const u16* g, u16* l) {
  __builtin_amdgcn_global_load_lds(
      (const __attribute__((address_space(1))) unsigned int*)g,
      (__attribute__((address_space(3))) unsigned int*)l, 16, 0, 0);
}

__device__ inline uint32_t cvt_pk_bf16(float lo, float hi) {
  uint32_t r;
  asm("v_cvt_pk_bf16_f32 %0, %1, %2" : "=v"(r) : "v"(lo), "v"(hi));
  return r;
}

// ---------------- LayerNorm: fp32 in -> bf16 out ----------------
__global__ __launch_bounds__(256) void ln_kernel(const float* __restrict__ x,
                                                 const float* __restrict__ gam,
                                                 const float* __restrict__ bet,
                                                 u16* __restrict__ out) {
  int row = blockIdx.x;
  int tid = threadIdx.x;
  const float4* xr = (const float4*)(x + (size_t)row * DMODEL);
  float4 v = xr[tid];
  float s = v.x + v.y + v.z + v.w;
  float ss = v.x * v.x + v.y * v.y + v.z * v.z + v.w * v.w;
#pragma unroll
  for (int m = 1; m < 64; m <<= 1) {
    s += __shfl_xor(s, m);
    ss += __shfl_xor(ss, m);
  }
  __shared__ float red[8];
  int w = tid >> 6, lane = tid & 63;
  if (lane == 0) { red[w] = s; red[4 + w] = ss; }
  __syncthreads();
  s = red[0] + red[1] + red[2] + red[3];
  ss = red[4] + red[5] + red[6] + red[7];
  float mu = s * (1.f / DMODEL);
  float var = ss * (1.f / DMODEL) - mu * mu;
  float rstd = rsqrtf(var + 1e-5f);
  float4 gv = ((const float4*)gam)[tid];
  float4 bv = ((const float4*)bet)[tid];
  u16x4 o;
  o.x = f2bf((v.x - mu) * rstd * gv.x + bv.x);
  o.y = f2bf((v.y - mu) * rstd * gv.y + bv.y);
  o.z = f2bf((v.z - mu) * rstd * gv.z + bv.z);
  o.w = f2bf((v.w - mu) * rstd * gv.w + bv.w);
  *(u16x4*)(out + (size_t)row * DMODEL + tid * 4) = o;
}

// ---------------- fp32 [R][C] -> bf16 [C][R] ----------------
__global__ __launch_bounds__(256) void transpose_cast(const float* __restrict__ in,
                                                      u16* __restrict__ out, int R, int C) {
  __shared__ u16 tile[32][33];
  int c0 = blockIdx.x * 32, r0 = blockIdx.y * 32;
  int tx = threadIdx.x & 31, grp = threadIdx.x >> 5;
#pragma unroll
  for (int i = 0; i < 4; i++) {
    int r = grp * 4 + i;
    tile[r][tx] = f2bf(in[(size_t)(r0 + r) * C + c0 + tx]);
  }
  __syncthreads();
#pragma unroll
  for (int i = 0; i < 4; i++) {
    int rr = grp * 4 + i;
    out[(size_t)(c0 + rr) * R + r0 + tx] = tile[tx][rr];
  }
}

// ---------------- V slice of qkv -> Vt[bh][dh][s] ----------------
__global__ __launch_bounds__(256) void transpose_v(const u16* __restrict__ qkv,
                                                   u16* __restrict__ vt) {
  __shared__ u16 tile[32][33];
  int bh = blockIdx.z;
  int b = bh >> 4;
  int s0 = blockIdx.x * 32, d0 = blockIdx.y * 32;
  int h = bh & 15;
  int tx = threadIdx.x & 31, grp = threadIdx.x >> 5;
#pragma unroll
  for (int i = 0; i < 4; i++) {
    int sl = grp * 4 + i;
    tile[sl][tx] = qkv[(size_t)((s0 + sl) * BATCH + b) * 3072 + 2048 + h * DHEAD + d0 + tx];
  }
  __syncthreads();
#pragma unroll
  for (int i = 0; i < 4; i++) {
    int dl = grp * 4 + i;
    vt[((size_t)bh * DHEAD + d0 + dl) * S_LEN + s0 + tx] = tile[tx][dl];
  }
}

// ---------------- GEMM 128x128: C[M][N] = A[M][K](bf16) @ Bt[N][K](bf16)^T ----------------
// MODE 0: bf16 out.  MODE 1: fp32 out = acc + res.
// MODE 2: bf16 out = relu(acc + bias).  MODE 3: fp32 out = acc + bias + res.
template <int MODE>
__global__ __launch_bounds__(256) void gemm_bt(const u16* __restrict__ A,
                                               const u16* __restrict__ Bt, void* __restrict__ Cout,
                                               const float* __restrict__ bias,
                                               const float* __restrict__ res, int M, int N, int K) {
  __shared__ __align__(16) u16 As[128 * 32];
  __shared__ __align__(16) u16 Bs[128 * 32];
  int bm0 = blockIdx.y * 128, bn0 = blockIdx.x * 128;
  int tid = threadIdx.x, w = tid >> 6, lane = tid & 63;
  int g = lane >> 4, l15 = lane & 15;
  int wm = (w >> 1) * 64, wn = (w & 1) * 64;
  f32x4 acc[4][4];
#pragma unroll
  for (int i = 0; i < 4; i++)
#pragma unroll
    for (int j = 0; j < 4; j++) {
      f32x4 z = {0.f, 0.f, 0.f, 0.f};
      acc[i][j] = z;
    }
  for (int k0 = 0; k0 < K; k0 += 32) {
#pragma unroll
    for (int rd = 0; rd < 2; rd++) {
      int fb = (rd * 4 + w) * 512;       // wave-uniform LDS element base
      int lf = fb + lane * 8;            // this lane's element slot
      int r = lf >> 5, c = lf & 31;
      gload_lds16(A + (size_t)(bm0 + r) * K + k0 + c, &As[fb]);
      gload_lds16(Bt + (size_t)(bn0 + r) * K + k0 + c, &Bs[fb]);
    }
    __syncthreads();  // drains vmcnt before barrier
    bf16x8 af[4], bfr[4];
#pragma unroll
    for (int i = 0; i < 4; i++)
      af[i] = *(const bf16x8*)&As[(wm + i * 16 + l15) * 32 + g * 8];
#pragma unroll
    for (int i = 0; i < 4; i++)
      bfr[i] = *(const bf16x8*)&Bs[(wn + i * 16 + l15) * 32 + g * 8];
#pragma unroll
    for (int i = 0; i < 4; i++)
#pragma unroll
      for (int j = 0; j < 4; j++) acc[i][j] = mfma16(af[i], bfr[j], acc[i][j]);
    __syncthreads();
  }
#pragma unroll
  for (int i = 0; i < 4; i++)
#pragma unroll
    for (int j = 0; j < 4; j++) {
      int col = bn0 + wn + j * 16 + l15;
      float bval = (MODE == 2 || MODE == 3) ? bias[col] : 0.f;
#pragma unroll
      for (int r = 0; r < 4; r++) {
        int row = bm0 + wm + i * 16 + g * 4 + r;
        size_t idx = (size_t)row * N + col;
        float vacc = acc[i][j][r] + bval;
        if (MODE == 0)
          ((u16*)Cout)[idx] = f2bf(vacc);
        else if (MODE == 1)
          ((float*)Cout)[idx] = vacc + res[idx];
        else if (MODE == 2)
          ((u16*)Cout)[idx] = f2bf(fmaxf(vacc, 0.f));
        else
          ((float*)Cout)[idx] = vacc + res[idx];
      }
    }
}

// ---------------- GEMM 128x64 (for N=1024 cases: 512 blocks = 2/CU) ----------------
template <int MODE>
__global__ __launch_bounds__(256) void gemm_bt_n64(const u16* __restrict__ A,
                                                   const u16* __restrict__ Bt,
                                                   void* __restrict__ Cout,
                                                   const float* __restrict__ bias,
                                                   const float* __restrict__ res, int M, int N,
                                                   int K) {
  __shared__ __align__(16) u16 As[128 * 32];
  __shared__ __align__(16) u16 Bs[64 * 32];
  int bm0 = blockIdx.y * 128, bn0 = blockIdx.x * 64;
  int tid = threadIdx.x, w = tid >> 6, lane = tid & 63;
  int g = lane >> 4, l15 = lane & 15;
  int wm = (w >> 1) * 64, wn = (w & 1) * 32;  // 2x2 waves, wave tile 64x32
  f32x4 acc[4][2];
#pragma unroll
  for (int i = 0; i < 4; i++)
#pragma unroll
    for (int j = 0; j < 2; j++) {
      f32x4 z = {0.f, 0.f, 0.f, 0.f};
      acc[i][j] = z;
    }
  for (int k0 = 0; k0 < K; k0 += 32) {
#pragma unroll
    for (int rd = 0; rd < 2; rd++) {
      int fb = (rd * 4 + w) * 512;
      int lf = fb + lane * 8;
      int r = lf >> 5, c = lf & 31;
      gload_lds16(A + (size_t)(bm0 + r) * K + k0 + c, &As[fb]);
    }
    {
      int fb = w * 512;
      int lf = fb + lane * 8;
      int r = lf >> 5, c = lf & 31;
      gload_lds16(Bt + (size_t)(bn0 + r) * K + k0 + c, &Bs[fb]);
    }
    __syncthreads();
    bf16x8 af[4], bfr[2];
#pragma unroll
    for (int i = 0; i < 4; i++)
      af[i] = *(const bf16x8*)&As[(wm + i * 16 + l15) * 32 + g * 8];
#pragma unroll
    for (int j = 0; j < 2; j++)
      bfr[j] = *(const bf16x8*)&Bs[(wn + j * 16 + l15) * 32 + g * 8];
#pragma unroll
    for (int i = 0; i < 4; i++)
#pragma unroll
      for (int j = 0; j < 2; j++) acc[i][j] = mfma16(af[i], bfr[j], acc[i][j]);
    __syncthreads();
  }
#pragma unroll
  for (int i = 0; i < 4; i++)
#pragma unroll
    for (int j = 0; j < 2; j++) {
      int col = bn0 + wn + j * 16 + l15;
      float bval = (MODE == 2 || MODE == 3) ? bias[col] : 0.f;
#pragma unroll
      for (int r = 0; r < 4; r++) {
        int row = bm0 + wm + i * 16 + g * 4 + r;
        size_t idx = (size_t)row * N + col;
        float vacc = acc[i][j][r] + bval;
        if (MODE == 0)
          ((u16*)Cout)[idx] = f2bf(vacc);
        else if (MODE == 1)
          ((float*)Cout)[idx] = vacc + res[idx];
        else if (MODE == 2)
          ((u16*)Cout)[idx] = f2bf(fmaxf(vacc, 0.f));
        else
          ((float*)Cout)[idx] = vacc + res[idx];
      }
    }
}

// ---------------- flash attention v3: swapped QK^T, in-register P ----------------
// grid (S/128, B*H), 256 thr = 4 waves; wave owns 32 q rows (2 x 16).
// Swapped mfma(K,Q): lane holds S^T[t=16tt+4g+r][q=l15] -> softmax is lane-local + 2 shfl.
// P -> PV B-frag entirely in-register: cvt_pk pairs, then permlane32/16 swaps move
// t-bits (t4,t3) into lane bits (lane5,lane4), leaving reg=(t5,t2,t1) = k-chunk layout.
// PV swapped too: mfma(V^T, P^T) -> acc col=q=l15 (alpha rescale lane-local).
__global__ __launch_bounds__(256) void attn_kernel(const u16* __restrict__ qkv,
                                                   const u16* __restrict__ vt,
                                                   u16* __restrict__ ctx) {
  int bh = blockIdx.y;
  int b = bh >> 4, h = bh & 15;
  int tid = threadIdx.x, w = tid >> 6, lane = tid & 63;
  int g = lane >> 4, l15 = lane & 15;
  int lr = lane >> 3, ch = lane & 7;
  int q0 = blockIdx.x * 128 + w * 32;
  const float SCALE = 0.125f * 1.44269504f;  // 1/sqrt(64) * log2(e): exp2 domain

  __shared__ __align__(16) u16 ks[2][64 * 64];
  __shared__ __align__(16) u16 vs[2][64 * 64];

  // Q fragments: qf[qs][c] = Q[q0+qs*16+l15][c*32 + g*8 ..+7]
  bf16x8 qf[2][2];
#pragma unroll
  for (int qs = 0; qs < 2; qs++) {
    const u16* qp = qkv + ((size_t)(q0 + qs * 16 + l15) * BATCH + b) * 3072 + h * DHEAD;
    qf[qs][0] = *(const bf16x8*)(qp + g * 8);
    qf[qs][1] = *(const bf16x8*)(qp + 32 + g * 8);
  }

  f32x4 accT[2][4];  // [qs][n]: col=q=l15, row=dh=n*16+4g+r
#pragma unroll
  for (int qs = 0; qs < 2; qs++)
#pragma unroll
    for (int n = 0; n < 4; n++) {
      f32x4 z = {0.f, 0.f, 0.f, 0.f};
      accT[qs][n] = z;
    }
  float mrun[2] = {-1e30f, -1e30f}, lrun[2] = {0.f, 0.f};

  auto stage = [&](int t0, int buf) {
#pragma unroll
    for (int rd = 0; rd < 2; rd++) {
      int rb = w * 16 + rd * 8;
      int row = rb + lr;  // row & 7 == lr
      const u16* ksrc =
          qkv + ((size_t)(t0 + row) * BATCH + b) * 3072 + 1024 + h * DHEAD + (ch ^ lr) * 8;
      gload_lds16(ksrc, &ks[buf][rb * 64]);
      const u16* vsrc = vt + ((size_t)bh * DHEAD + row) * S_LEN + t0 + (ch ^ lr) * 8;
      gload_lds16(vsrc, &vs[buf][rb * 64]);
    }
  };

  stage(0, 0);
  __syncthreads();

  for (int it = 0; it < S_LEN / 64; ++it) {
    int cur = it & 1;
    if (it + 1 < S_LEN / 64) stage((it + 1) * 64, cur ^ 1);  // prefetch overlaps compute

    // ---- QK^T (swapped): scT[qs][tt][r] = S^T[16tt+4g+r][qs*16+l15] ----
    f32x4 scT[2][4];
#pragma unroll
    for (int tt = 0; tt < 4; tt++) {
      int row = tt * 16 + l15;
      bf16x8 kf0 = *(const bf16x8*)&ks[cur][row * 64 + ((g ^ (row & 7)) * 8)];
      bf16x8 kf1 = *(const bf16x8*)&ks[cur][row * 64 + (((4 + g) ^ (row & 7)) * 8)];
#pragma unroll
      for (int qs = 0; qs < 2; qs++) {
        f32x4 z = {0.f, 0.f, 0.f, 0.f};
        z = mfma16(kf0, qf[qs][0], z);
        z = mfma16(kf1, qf[qs][1], z);
        scT[qs][tt] = z * SCALE;
      }
    }

    // ---- softmax + in-register P repack ----
    bf16x8 pb[2][2];  // [qs][s2] PV B-frags
#pragma unroll
    for (int qs = 0; qs < 2; qs++) {
      float pm = fmaxf(fmaxf(scT[qs][0][0], scT[qs][0][1]), fmaxf(scT[qs][0][2], scT[qs][0][3]));
#pragma unroll
      for (int tt = 1; tt < 4; tt++)
        pm = fmaxf(pm, fmaxf(fmaxf(scT[qs][tt][0], scT[qs][tt][1]),
                             fmaxf(scT[qs][tt][2], scT[qs][tt][3])));
      pm = fmaxf(pm, __shfl_xor(pm, 16));
      pm = fmaxf(pm, __shfl_xor(pm, 32));
      float mn = fmaxf(mrun[qs], pm);
      float al = __builtin_amdgcn_exp2f(mrun[qs] - mn);
      mrun[qs] = mn;
      float p[4][4];
      float psum = 0.f;
#pragma unroll
      for (int tt = 0; tt < 4; tt++)
#pragma unroll
        for (int r = 0; r < 4; r++) {
          p[tt][r] = __builtin_amdgcn_exp2f(scT[qs][tt][r] - mn);
          psum += p[tt][r];
        }
      psum += __shfl_xor(psum, 16);
      psum += __shfl_xor(psum, 32);
      lrun[qs] = lrun[qs] * al + psum;
#pragma unroll
      for (int n = 0; n < 4; n++) accT[qs][n] *= al;
      // pack: P32[tt][m] = (bf16(p[tt][2m]) | bf16(p[tt][2m+1])<<16); reg=(t5,t4,t1), lane=(t3,t2)
      uint32_t P32[4][2];
#pragma unroll
      for (int tt = 0; tt < 4; tt++)
#pragma unroll
        for (int m = 0; m < 2; m++) P32[tt][m] = cvt_pk_bf16(p[tt][2 * m], p[tt][2 * m + 1]);
      // permlane32: swap reg-bit t4 with lane5; permlane16: swap reg-bit t3 with lane4
#pragma unroll
      for (int t5 = 0; t5 < 2; t5++)
#pragma unroll
        for (int m = 0; m < 2; m++) {
          asm("v_permlane32_swap_b32 %0, %1" : "+v"(P32[2 * t5][m]), "+v"(P32[2 * t5 + 1][m]));
          asm("v_permlane16_swap_b32 %0, %1" : "+v"(P32[2 * t5][m]), "+v"(P32[2 * t5 + 1][m]));
        }
      // now P32[2*s2 + t2][t1]: frag s2 u32 jj=(t2,t1)
#pragma unroll
      for (int s2 = 0; s2 < 2; s2++) {
        union { uint32_t u[4]; bf16x8 v; } uu;
        uu.u[0] = P32[2 * s2][0];
        uu.u[1] = P32[2 * s2][1];
        uu.u[2] = P32[2 * s2 + 1][0];
        uu.u[3] = P32[2 * s2 + 1][1];
        pb[qs][s2] = uu.v;
      }
    }

    // ---- PV (swapped): accT[qs][n] += V^T-frag * P^T-frag ----
#pragma unroll
    for (int n = 0; n < 4; n++)
#pragma unroll
      for (int s2 = 0; s2 < 2; s2++) {
        int vrow = n * 16 + l15;
        int vchunk = (s2 * 4 + g) ^ (vrow & 7);
        bf16x8 vf = *(const bf16x8*)&vs[cur][vrow * 64 + vchunk * 8];
        accT[0][n] = mfma16(vf, pb[0][s2], accT[0][n]);
        accT[1][n] = mfma16(vf, pb[1][s2], accT[1][n]);
      }
    __syncthreads();  // drains vmcnt (prefetch landed) + orders K/V buffer reuse
  }

#pragma unroll
  for (int qs = 0; qs < 2; qs++) {
    float inv = 1.f / lrun[qs];
    int srow = q0 + qs * 16 + l15;
#pragma unroll
    for (int n = 0; n < 4; n++) {
      u16x4 o;
      o.x = f2bf(accT[qs][n][0] * inv);
      o.y = f2bf(accT[qs][n][1] * inv);
      o.z = f2bf(accT[qs][n][2] * inv);
      o.w = f2bf(accT[qs][n][3] * inv);
      *(u16x4*)(ctx + ((size_t)srow * BATCH + b) * DMODEL + h * DHEAD + n * 16 + 4 * g) = o;
    }
  }
}

extern "C" void kernel_launch(void* const* d_in, const int* in_sizes, int n_in, void* d_out,
                              int out_size, void* d_ws, size_t ws_size, hipStream_t stream) {
  (void)in_sizes; (void)n_in; (void)out_size; (void)ws_size;
  const float* x    = (const float*)d_in[0];
  const float* wq   = (const float*)d_in[1];
  const float* wk   = (const float*)d_in[2];
  const float* wv   = (const float*)d_in[3];
  const float* wo   = (const float*)d_in[4];
  const float* ln1g = (const float*)d_in[5];
  const float* ln1b = (const float*)d_in[6];
  const float* ln2g = (const float*)d_in[7];
  const float* ln2b = (const float*)d_in[8];
  const float* w1   = (const float*)d_in[9];
  const float* b1   = (const float*)d_in[10];
  const float* w2   = (const float*)d_in[11];
  const float* b2   = (const float*)d_in[12];

  char* ws = (char*)d_ws;
  size_t off = 0;
  auto alloc = [&](size_t bytes) {
    void* p = ws + off;
    off += (bytes + 255) & ~(size_t)255;
    return p;
  };
  u16* yb    = (u16*)alloc((size_t)MROWS * DMODEL * 2);
  u16* wqkvt = (u16*)alloc((size_t)3072 * 1024 * 2);
  u16* wot   = (u16*)alloc((size_t)1024 * 1024 * 2);
  u16* w1t   = (u16*)alloc((size_t)4096 * 1024 * 2);
  u16* w2t   = (u16*)alloc((size_t)1024 * 4096 * 2);
  u16* qkvb  = (u16*)alloc((size_t)MROWS * 3072 * 2);
  u16* vtb   = (u16*)alloc((size_t)BATCH * NHEAD * DHEAD * S_LEN * 2);
  u16* ctxb  = (u16*)alloc((size_t)MROWS * DMODEL * 2);
  float* x1  = (float*)alloc((size_t)MROWS * DMODEL * 4);
  u16* zb    = (u16*)alloc((size_t)MROWS * DMODEL * 2);
  u16* hb    = (u16*)alloc((size_t)MROWS * FFDIM * 2);

  // sublayer 0
  ln_kernel<<<MROWS, 256, 0, stream>>>(x, ln1g, ln1b, yb);
  transpose_cast<<<dim3(32, 32), 256, 0, stream>>>(wq, wqkvt, 1024, 1024);
  transpose_cast<<<dim3(32, 32), 256, 0, stream>>>(wk, wqkvt + 1024 * 1024, 1024, 1024);
  transpose_cast<<<dim3(32, 32), 256, 0, stream>>>(wv, wqkvt + 2 * 1024 * 1024, 1024, 1024);
  transpose_cast<<<dim3(32, 32), 256, 0, stream>>>(wo, wot, 1024, 1024);
  transpose_cast<<<dim3(128, 32), 256, 0, stream>>>(w1, w1t, 1024, 4096);
  transpose_cast<<<dim3(32, 128), 256, 0, stream>>>(w2, w2t, 4096, 1024);

  gemm_bt<0><<<dim3(3072 / 128, 4096 / 128), 256, 0, stream>>>(yb, wqkvt, qkvb, nullptr, nullptr,
                                                               4096, 3072, 1024);
  transpose_v<<<dim3(64, 2, 32), 256, 0, stream>>>(qkvb, vtb);
  attn_kernel<<<dim3(16, 32), 256, 0, stream>>>(qkvb, vtb, ctxb);
  gemm_bt_n64<1><<<dim3(16, 32), 256, 0, stream>>>(ctxb, wot, x1, nullptr, x, 4096, 1024, 1024);

  // sublayer 1
  ln_kernel<<<MROWS, 256, 0, stream>>>(x1, ln2g, ln2b, zb);
  gemm_bt<2><<<dim3(32, 32), 256, 0, stream>>>(zb, w1t, hb, b1, nullptr, 4096, 4096, 1024);
  gemm_bt_n64<3><<<dim3(16, 32), 256, 0, stream>>>(hb, w2t, d_out, b2, x1, 4096, 1024, 4096);
}

// Round 4
// 267.428 us; speedup vs baseline: 1.7701x; 1.1177x over previous
//
#include <hip/hip_runtime.h>
#include <hip/hip_bf16.h>
#include <stdint.h>

// Transformer layer: S=2048, B=2, D=1024, H=16, DH=64, FF=4096. fp32 in/out.
// Strategy: fp32 LN/softmax/accum, bf16 MFMA (16x16x32) for all GEMMs.

#define S_LEN 2048
#define BATCH 2
#define DMODEL 1024
#define NHEAD 16
#define DHEAD 64
#define FFDIM 4096
#define MROWS (S_LEN * BATCH)  // 4096 rows, row index = s*B + b

typedef unsigned short u16;
typedef __attribute__((ext_vector_type(8))) __bf16 bf16x8;
typedef __attribute__((ext_vector_type(4))) float f32x4;
typedef __attribute__((ext_vector_type(4))) u16 u16x4;

__device__ inline u16 f2bf(float f) {
  union { float f; unsigned u; } v; v.f = f;
  unsigned r = v.u + 0x7fffu + ((v.u >> 16) & 1u);  // round-to-nearest-even
  return (u16)(r >> 16);
}

__device__ inline f32x4 mfma16(bf16x8 a, bf16x8 b, f32x4 c) {
  return __builtin_amdgcn_mfma_f32_16x16x32_bf16(a, b, c, 0, 0, 0);
}

// async global->LDS, 16B per lane. LDS dest must be wave-uniform base; HW adds lane*16.
__device__ inline void gload_lds16(const u16* g, u16* l) {
  __builtin_amdgcn_global_load_lds(
      (const __attribute__((address_space(1))) unsigned int*)g,
      (__attribute__((address_space(3))) unsigned int*)l, 16, 0, 0);
}

__device__ inline uint32_t cvt_pk_bf16(float lo, float hi) {
  uint32_t r;
  asm("v_cvt_pk_bf16_f32 %0, %1, %2" : "=v"(r) : "v"(lo), "v"(hi));
  return r;
}

// ---------------- LayerNorm: fp32 in -> bf16 out ----------------
__global__ __launch_bounds__(256) void ln_kernel(const float* __restrict__ x,
                                                 const float* __restrict__ gam,
                                                 const float* __restrict__ bet,
                                                 u16* __restrict__ out) {
  int row = blockIdx.x;
  int tid = threadIdx.x;
  const float4* xr = (const float4*)(x + (size_t)row * DMODEL);
  float4 v = xr[tid];
  float s = v.x + v.y + v.z + v.w;
  float ss = v.x * v.x + v.y * v.y + v.z * v.z + v.w * v.w;
#pragma unroll
  for (int m = 1; m < 64; m <<= 1) {
    s += __shfl_xor(s, m);
    ss += __shfl_xor(ss, m);
  }
  __shared__ float red[8];
  int w = tid >> 6, lane = tid & 63;
  if (lane == 0) { red[w] = s; red[4 + w] = ss; }
  __syncthreads();
  s = red[0] + red[1] + red[2] + red[3];
  ss = red[4] + red[5] + red[6] + red[7];
  float mu = s * (1.f / DMODEL);
  float var = ss * (1.f / DMODEL) - mu * mu;
  float rstd = rsqrtf(var + 1e-5f);
  float4 gv = ((const float4*)gam)[tid];
  float4 bv = ((const float4*)bet)[tid];
  u16x4 o;
  o.x = f2bf((v.x - mu) * rstd * gv.x + bv.x);
  o.y = f2bf((v.y - mu) * rstd * gv.y + bv.y);
  o.z = f2bf((v.z - mu) * rstd * gv.z + bv.z);
  o.w = f2bf((v.w - mu) * rstd * gv.w + bv.w);
  *(u16x4*)(out + (size_t)row * DMODEL + tid * 4) = o;
}

// ---------------- fp32 [R][C] -> bf16 [C][R] ----------------
__global__ __launch_bounds__(256) void transpose_cast(const float* __restrict__ in,
                                                      u16* __restrict__ out, int R, int C) {
  __shared__ u16 tile[32][33];
  int c0 = blockIdx.x * 32, r0 = blockIdx.y * 32;
  int tx = threadIdx.x & 31, grp = threadIdx.x >> 5;
#pragma unroll
  for (int i = 0; i < 4; i++) {
    int r = grp * 4 + i;
    tile[r][tx] = f2bf(in[(size_t)(r0 + r) * C + c0 + tx]);
  }
  __syncthreads();
#pragma unroll
  for (int i = 0; i < 4; i++) {
    int rr = grp * 4 + i;
    out[(size_t)(c0 + rr) * R + r0 + tx] = tile[tx][rr];
  }
}

// ---------------- V slice of qkv -> Vt[bh][dh][s] ----------------
__global__ __launch_bounds__(256) void transpose_v(const u16* __restrict__ qkv,
                                                   u16* __restrict__ vt) {
  __shared__ u16 tile[32][33];
  int bh = blockIdx.z;
  int b = bh >> 4;
  int s0 = blockIdx.x * 32, d0 = blockIdx.y * 32;
  int h = bh & 15;
  int tx = threadIdx.x & 31, grp = threadIdx.x >> 5;
#pragma unroll
  for (int i = 0; i < 4; i++) {
    int sl = grp * 4 + i;
    tile[sl][tx] = qkv[(size_t)((s0 + sl) * BATCH + b) * 3072 + 2048 + h * DHEAD + d0 + tx];
  }
  __syncthreads();
#pragma unroll
  for (int i = 0; i < 4; i++) {
    int dl = grp * 4 + i;
    vt[((size_t)bh * DHEAD + d0 + dl) * S_LEN + s0 + tx] = tile[tx][dl];
  }
}

// ---------------- GEMM v2: BK=64, XOR-swizzled LDS, double-buffered 2-phase pipeline ----
// C[M][N] = A[M][K](bf16) @ Bt[N][K](bf16)^T.  BM=128, BN in {128,64}.
// LDS tile [row][64] with 16B chunk swizzle chunk^=(row&7); staged via gload_lds with
// pre-swizzled global source (rule 21c).  One barrier per 64-K tile; next tile's
// global_load_lds issued before computing current (T3-minimum 2-phase).
// XCD-chunked block swizzle (T1) for A-panel L2 reuse.
// MODE 0: bf16 out.  MODE 1: fp32 out = acc + res.
// MODE 2: bf16 out = relu(acc + bias).  MODE 3: fp32 out = acc + bias + res.
template <int MODE, int BN>
__global__ __launch_bounds__(256) void gemm_bt(const u16* __restrict__ A,
                                               const u16* __restrict__ Bt, void* __restrict__ Cout,
                                               const float* __restrict__ bias,
                                               const float* __restrict__ res, int M, int N, int K) {
  __shared__ __align__(16) u16 As[2][128 * 64];
  __shared__ __align__(16) u16 Bs[2][BN * 64];

  // XCD-chunked bijective block swizzle (grids here are all %8==0)
  int nwg = gridDim.x * gridDim.y;
  int f = blockIdx.y * gridDim.x + blockIdx.x;
  int nf = ((nwg & 7) == 0) ? ((f & 7) * (nwg >> 3) + (f >> 3)) : f;
  int bx = nf % gridDim.x, by = nf / gridDim.x;

  int bm0 = by * 128, bn0 = bx * BN;
  int tid = threadIdx.x, w = tid >> 6, lane = tid & 63;
  int g = lane >> 4, l15 = lane & 15;
  int lr = lane >> 3, ch = lane & 7;
  int srcch = (ch ^ lr) * 8;  // pre-swizzled 16B-chunk column offset (elements)
  int wm = (w >> 1) * 64, wn = (w & 1) * (BN / 2);
  const int NJ = BN / 32;  // wave n-frags per k-step

  f32x4 acc[4][NJ];
#pragma unroll
  for (int i = 0; i < 4; i++)
#pragma unroll
    for (int j = 0; j < NJ; j++) {
      f32x4 z = {0.f, 0.f, 0.f, 0.f};
      acc[i][j] = z;
    }

  auto stage = [&](int k0, int buf) {
#pragma unroll
    for (int rd = 0; rd < 4; rd++) {
      int rb = (rd * 4 + w) * 8;  // row base; this lane's row = rb + lr, row&7 == lr
      gload_lds16(A + (size_t)(bm0 + rb + lr) * K + k0 + srcch, &As[buf][rb * 64]);
    }
#pragma unroll
    for (int rd = 0; rd < BN / 32; rd++) {
      int rb = (rd * 4 + w) * 8;
      gload_lds16(Bt + (size_t)(bn0 + rb + lr) * K + k0 + srcch, &Bs[buf][rb * 64]);
    }
  };

  int nkt = K >> 6;
  stage(0, 0);
  __syncthreads();  // drain initial stage

  for (int kt = 0; kt < nkt; ++kt) {
    int cur = kt & 1;
    if (kt + 1 < nkt) stage((kt + 1) << 6, cur ^ 1);  // prefetch overlaps compute
#pragma unroll
    for (int kk = 0; kk < 2; kk++) {
      bf16x8 af[4], bfr[NJ];
#pragma unroll
      for (int i = 0; i < 4; i++) {
        int row = wm + i * 16 + l15;
        af[i] = *(const bf16x8*)&As[cur][row * 64 + (((kk * 4 + g) ^ (row & 7)) * 8)];
      }
#pragma unroll
      for (int j = 0; j < NJ; j++) {
        int row = wn + j * 16 + l15;
        bfr[j] = *(const bf16x8*)&Bs[cur][row * 64 + (((kk * 4 + g) ^ (row & 7)) * 8)];
      }
#pragma unroll
      for (int i = 0; i < 4; i++)
#pragma unroll
        for (int j = 0; j < NJ; j++) acc[i][j] = mfma16(af[i], bfr[j], acc[i][j]);
    }
    __syncthreads();  // drains prefetch vmcnt; buffer-swap safety
  }

  // epilogue: D layout col = lane&15, row = 4*(lane>>4) + r
#pragma unroll
  for (int i = 0; i < 4; i++)
#pragma unroll
    for (int j = 0; j < NJ; j++) {
      int col = bn0 + wn + j * 16 + l15;
      float bval = (MODE == 2 || MODE == 3) ? bias[col] : 0.f;
#pragma unroll
      for (int r = 0; r < 4; r++) {
        int row = bm0 + wm + i * 16 + g * 4 + r;
        size_t idx = (size_t)row * N + col;
        float vacc = acc[i][j][r] + bval;
        if (MODE == 0)
          ((u16*)Cout)[idx] = f2bf(vacc);
        else if (MODE == 1)
          ((float*)Cout)[idx] = vacc + res[idx];
        else if (MODE == 2)
          ((u16*)Cout)[idx] = f2bf(fmaxf(vacc, 0.f));
        else
          ((float*)Cout)[idx] = vacc + res[idx];
      }
    }
}

// ---------------- flash attention v3: swapped QK^T, in-register P ----------------
// grid (S/128, B*H), 256 thr = 4 waves; wave owns 32 q rows (2 x 16).
// Swapped mfma(K,Q): lane holds S^T[t=16tt+4g+r][q=l15] -> softmax is lane-local + 2 shfl.
// P -> PV B-frag entirely in-register: cvt_pk pairs, then permlane32/16 swaps move
// t-bits (t4,t3) into lane bits (lane5,lane4), leaving reg=(t5,t2,t1) = k-chunk layout.
// PV swapped too: mfma(V^T, P^T) -> acc col=q=l15 (alpha rescale lane-local).
__global__ __launch_bounds__(256) void attn_kernel(const u16* __restrict__ qkv,
                                                   const u16* __restrict__ vt,
                                                   u16* __restrict__ ctx) {
  int bh = blockIdx.y;
  int b = bh >> 4, h = bh & 15;
  int tid = threadIdx.x, w = tid >> 6, lane = tid & 63;
  int g = lane >> 4, l15 = lane & 15;
  int lr = lane >> 3, ch = lane & 7;
  int q0 = blockIdx.x * 128 + w * 32;
  const float SCALE = 0.125f * 1.44269504f;  // 1/sqrt(64) * log2(e): exp2 domain

  __shared__ __align__(16) u16 ks[2][64 * 64];
  __shared__ __align__(16) u16 vs[2][64 * 64];

  // Q fragments: qf[qs][c] = Q[q0+qs*16+l15][c*32 + g*8 ..+7]
  bf16x8 qf[2][2];
#pragma unroll
  for (int qs = 0; qs < 2; qs++) {
    const u16* qp = qkv + ((size_t)(q0 + qs * 16 + l15) * BATCH + b) * 3072 + h * DHEAD;
    qf[qs][0] = *(const bf16x8*)(qp + g * 8);
    qf[qs][1] = *(const bf16x8*)(qp + 32 + g * 8);
  }

  f32x4 accT[2][4];  // [qs][n]: col=q=l15, row=dh=n*16+4g+r
#pragma unroll
  for (int qs = 0; qs < 2; qs++)
#pragma unroll
    for (int n = 0; n < 4; n++) {
      f32x4 z = {0.f, 0.f, 0.f, 0.f};
      accT[qs][n] = z;
    }
  float mrun[2] = {-1e30f, -1e30f}, lrun[2] = {0.f, 0.f};

  auto stage = [&](int t0, int buf) {
#pragma unroll
    for (int rd = 0; rd < 2; rd++) {
      int rb = w * 16 + rd * 8;
      int row = rb + lr;  // row & 7 == lr
      const u16* ksrc =
          qkv + ((size_t)(t0 + row) * BATCH + b) * 3072 + 1024 + h * DHEAD + (ch ^ lr) * 8;
      gload_lds16(ksrc, &ks[buf][rb * 64]);
      const u16* vsrc = vt + ((size_t)bh * DHEAD + row) * S_LEN + t0 + (ch ^ lr) * 8;
      gload_lds16(vsrc, &vs[buf][rb * 64]);
    }
  };

  stage(0, 0);
  __syncthreads();

  for (int it = 0; it < S_LEN / 64; ++it) {
    int cur = it & 1;
    if (it + 1 < S_LEN / 64) stage((it + 1) * 64, cur ^ 1);  // prefetch overlaps compute

    // ---- QK^T (swapped): scT[qs][tt][r] = S^T[16tt+4g+r][qs*16+l15] ----
    f32x4 scT[2][4];
#pragma unroll
    for (int tt = 0; tt < 4; tt++) {
      int row = tt * 16 + l15;
      bf16x8 kf0 = *(const bf16x8*)&ks[cur][row * 64 + ((g ^ (row & 7)) * 8)];
      bf16x8 kf1 = *(const bf16x8*)&ks[cur][row * 64 + (((4 + g) ^ (row & 7)) * 8)];
#pragma unroll
      for (int qs = 0; qs < 2; qs++) {
        f32x4 z = {0.f, 0.f, 0.f, 0.f};
        z = mfma16(kf0, qf[qs][0], z);
        z = mfma16(kf1, qf[qs][1], z);
        scT[qs][tt] = z * SCALE;
      }
    }

    // ---- softmax + in-register P repack ----
    bf16x8 pb[2][2];  // [qs][s2] PV B-frags
#pragma unroll
    for (int qs = 0; qs < 2; qs++) {
      float pm = fmaxf(fmaxf(scT[qs][0][0], scT[qs][0][1]), fmaxf(scT[qs][0][2], scT[qs][0][3]));
#pragma unroll
      for (int tt = 1; tt < 4; tt++)
        pm = fmaxf(pm, fmaxf(fmaxf(scT[qs][tt][0], scT[qs][tt][1]),
                             fmaxf(scT[qs][tt][2], scT[qs][tt][3])));
      pm = fmaxf(pm, __shfl_xor(pm, 16));
      pm = fmaxf(pm, __shfl_xor(pm, 32));
      float mn = fmaxf(mrun[qs], pm);
      float al = __builtin_amdgcn_exp2f(mrun[qs] - mn);
      mrun[qs] = mn;
      float p[4][4];
      float psum = 0.f;
#pragma unroll
      for (int tt = 0; tt < 4; tt++)
#pragma unroll
        for (int r = 0; r < 4; r++) {
          p[tt][r] = __builtin_amdgcn_exp2f(scT[qs][tt][r] - mn);
          psum += p[tt][r];
        }
      psum += __shfl_xor(psum, 16);
      psum += __shfl_xor(psum, 32);
      lrun[qs] = lrun[qs] * al + psum;
#pragma unroll
      for (int n = 0; n < 4; n++) accT[qs][n] *= al;
      // pack: P32[tt][m] = (bf16(p[tt][2m]) | bf16(p[tt][2m+1])<<16); reg=(t5,t4,t1), lane=(t3,t2)
      uint32_t P32[4][2];
#pragma unroll
      for (int tt = 0; tt < 4; tt++)
#pragma unroll
        for (int m = 0; m < 2; m++) P32[tt][m] = cvt_pk_bf16(p[tt][2 * m], p[tt][2 * m + 1]);
      // permlane32: swap reg-bit t4 with lane5; permlane16: swap reg-bit t3 with lane4
#pragma unroll
      for (int t5 = 0; t5 < 2; t5++)
#pragma unroll
        for (int m = 0; m < 2; m++) {
          asm("v_permlane32_swap_b32 %0, %1" : "+v"(P32[2 * t5][m]), "+v"(P32[2 * t5 + 1][m]));
          asm("v_permlane16_swap_b32 %0, %1" : "+v"(P32[2 * t5][m]), "+v"(P32[2 * t5 + 1][m]));
        }
      // now P32[2*s2 + t2][t1]: frag s2 u32 jj=(t2,t1)
#pragma unroll
      for (int s2 = 0; s2 < 2; s2++) {
        union { uint32_t u[4]; bf16x8 v; } uu;
        uu.u[0] = P32[2 * s2][0];
        uu.u[1] = P32[2 * s2][1];
        uu.u[2] = P32[2 * s2 + 1][0];
        uu.u[3] = P32[2 * s2 + 1][1];
        pb[qs][s2] = uu.v;
      }
    }

    // ---- PV (swapped): accT[qs][n] += V^T-frag * P^T-frag ----
#pragma unroll
    for (int n = 0; n < 4; n++)
#pragma unroll
      for (int s2 = 0; s2 < 2; s2++) {
        int vrow = n * 16 + l15;
        int vchunk = (s2 * 4 + g) ^ (vrow & 7);
        bf16x8 vf = *(const bf16x8*)&vs[cur][vrow * 64 + vchunk * 8];
        accT[0][n] = mfma16(vf, pb[0][s2], accT[0][n]);
        accT[1][n] = mfma16(vf, pb[1][s2], accT[1][n]);
      }
    __syncthreads();  // drains vmcnt (prefetch landed) + orders K/V buffer reuse
  }

#pragma unroll
  for (int qs = 0; qs < 2; qs++) {
    float inv = 1.f / lrun[qs];
    int srow = q0 + qs * 16 + l15;
#pragma unroll
    for (int n = 0; n < 4; n++) {
      u16x4 o;
      o.x = f2bf(accT[qs][n][0] * inv);
      o.y = f2bf(accT[qs][n][1] * inv);
      o.z = f2bf(accT[qs][n][2] * inv);
      o.w = f2bf(accT[qs][n][3] * inv);
      *(u16x4*)(ctx + ((size_t)srow * BATCH + b) * DMODEL + h * DHEAD + n * 16 + 4 * g) = o;
    }
  }
}

extern "C" void kernel_launch(void* const* d_in, const int* in_sizes, int n_in, void* d_out,
                              int out_size, void* d_ws, size_t ws_size, hipStream_t stream) {
  (void)in_sizes; (void)n_in; (void)out_size; (void)ws_size;
  const float* x    = (const float*)d_in[0];
  const float* wq   = (const float*)d_in[1];
  const float* wk   = (const float*)d_in[2];
  const float* wv   = (const float*)d_in[3];
  const float* wo   = (const float*)d_in[4];
  const float* ln1g = (const float*)d_in[5];
  const float* ln1b = (const float*)d_in[6];
  const float* ln2g = (const float*)d_in[7];
  const float* ln2b = (const float*)d_in[8];
  const float* w1   = (const float*)d_in[9];
  const float* b1   = (const float*)d_in[10];
  const float* w2   = (const float*)d_in[11];
  const float* b2   = (const float*)d_in[12];

  char* ws = (char*)d_ws;
  size_t off = 0;
  auto alloc = [&](size_t bytes) {
    void* p = ws + off;
    off += (bytes + 255) & ~(size_t)255;
    return p;
  };
  u16* yb    = (u16*)alloc((size_t)MROWS * DMODEL * 2);
  u16* wqkvt = (u16*)alloc((size_t)3072 * 1024 * 2);
  u16* wot   = (u16*)alloc((size_t)1024 * 1024 * 2);
  u16* w1t   = (u16*)alloc((size_t)4096 * 1024 * 2);
  u16* w2t   = (u16*)alloc((size_t)1024 * 4096 * 2);
  u16* qkvb  = (u16*)alloc((size_t)MROWS * 3072 * 2);
  u16* vtb   = (u16*)alloc((size_t)BATCH * NHEAD * DHEAD * S_LEN * 2);
  u16* ctxb  = (u16*)alloc((size_t)MROWS * DMODEL * 2);
  float* x1  = (float*)alloc((size_t)MROWS * DMODEL * 4);
  u16* zb    = (u16*)alloc((size_t)MROWS * DMODEL * 2);
  u16* hb    = (u16*)alloc((size_t)MROWS * FFDIM * 2);

  // sublayer 0
  ln_kernel<<<MROWS, 256, 0, stream>>>(x, ln1g, ln1b, yb);
  transpose_cast<<<dim3(32, 32), 256, 0, stream>>>(wq, wqkvt, 1024, 1024);
  transpose_cast<<<dim3(32, 32), 256, 0, stream>>>(wk, wqkvt + 1024 * 1024, 1024, 1024);
  transpose_cast<<<dim3(32, 32), 256, 0, stream>>>(wv, wqkvt + 2 * 1024 * 1024, 1024, 1024);
  transpose_cast<<<dim3(32, 32), 256, 0, stream>>>(wo, wot, 1024, 1024);
  transpose_cast<<<dim3(128, 32), 256, 0, stream>>>(w1, w1t, 1024, 4096);
  transpose_cast<<<dim3(32, 128), 256, 0, stream>>>(w2, w2t, 4096, 1024);

  gemm_bt<0, 128><<<dim3(3072 / 128, 4096 / 128), 256, 0, stream>>>(yb, wqkvt, qkvb, nullptr,
                                                                    nullptr, 4096, 3072, 1024);
  transpose_v<<<dim3(64, 2, 32), 256, 0, stream>>>(qkvb, vtb);
  attn_kernel<<<dim3(16, 32), 256, 0, stream>>>(qkvb, vtb, ctxb);
  gemm_bt<1, 64><<<dim3(16, 32), 256, 0, stream>>>(ctxb, wot, x1, nullptr, x, 4096, 1024, 1024);

  // sublayer 1
  ln_kernel<<<MROWS, 256, 0, stream>>>(x1, ln2g, ln2b, zb);
  gemm_bt<2, 128><<<dim3(32, 32), 256, 0, stream>>>(zb, w1t, hb, b1, nullptr, 4096, 4096, 1024);
  gemm_bt<3, 64><<<dim3(16, 32), 256, 0, stream>>>(hb, w2t, d_out, b2, x1, 4096, 1024, 4096);
}

// Round 5
// 260.414 us; speedup vs baseline: 1.8178x; 1.0269x over previous
//
#include <hip/hip_runtime.h>
#include <hip/hip_bf16.h>
#include <stdint.h>

// Transformer layer: S=2048, B=2, D=1024, H=16, DH=64, FF=4096. fp32 in/out.
// Strategy: fp32 LN/softmax/accum, bf16 MFMA (16x16x32) for all GEMMs.

#define S_LEN 2048
#define BATCH 2
#define DMODEL 1024
#define NHEAD 16
#define DHEAD 64
#define FFDIM 4096
#define MROWS (S_LEN * BATCH)  // 4096 rows, row index = s*B + b

typedef unsigned short u16;
typedef __attribute__((ext_vector_type(8))) __bf16 bf16x8;
typedef __attribute__((ext_vector_type(4))) float f32x4;
typedef __attribute__((ext_vector_type(4))) u16 u16x4;

__device__ inline u16 f2bf(float f) {
  union { float f; unsigned u; } v; v.f = f;
  unsigned r = v.u + 0x7fffu + ((v.u >> 16) & 1u);  // round-to-nearest-even
  return (u16)(r >> 16);
}

__device__ inline f32x4 mfma16(bf16x8 a, bf16x8 b, f32x4 c) {
  return __builtin_amdgcn_mfma_f32_16x16x32_bf16(a, b, c, 0, 0, 0);
}

// async global->LDS, 16B per lane. LDS dest must be wave-uniform base; HW adds lane*16.
__device__ inline void gload_lds16(const u16* g, u16* l) {
  __builtin_amdgcn_global_load_lds(
      (const __attribute__((address_space(1))) unsigned int*)g,
      (__attribute__((address_space(3))) unsigned int*)l, 16, 0, 0);
}

__device__ inline uint32_t cvt_pk_bf16(float lo, float hi) {
  uint32_t r;
  asm("v_cvt_pk_bf16_f32 %0, %1, %2" : "=v"(r) : "v"(lo), "v"(hi));
  return r;
}

// ---------------- LayerNorm: fp32 in -> bf16 out ----------------
__global__ __launch_bounds__(256) void ln_kernel(const float* __restrict__ x,
                                                 const float* __restrict__ gam,
                                                 const float* __restrict__ bet,
                                                 u16* __restrict__ out) {
  int row = blockIdx.x;
  int tid = threadIdx.x;
  const float4* xr = (const float4*)(x + (size_t)row * DMODEL);
  float4 v = xr[tid];
  float s = v.x + v.y + v.z + v.w;
  float ss = v.x * v.x + v.y * v.y + v.z * v.z + v.w * v.w;
#pragma unroll
  for (int m = 1; m < 64; m <<= 1) {
    s += __shfl_xor(s, m);
    ss += __shfl_xor(ss, m);
  }
  __shared__ float red[8];
  int w = tid >> 6, lane = tid & 63;
  if (lane == 0) { red[w] = s; red[4 + w] = ss; }
  __syncthreads();
  s = red[0] + red[1] + red[2] + red[3];
  ss = red[4] + red[5] + red[6] + red[7];
  float mu = s * (1.f / DMODEL);
  float var = ss * (1.f / DMODEL) - mu * mu;
  float rstd = rsqrtf(var + 1e-5f);
  float4 gv = ((const float4*)gam)[tid];
  float4 bv = ((const float4*)bet)[tid];
  u16x4 o;
  o.x = f2bf((v.x - mu) * rstd * gv.x + bv.x);
  o.y = f2bf((v.y - mu) * rstd * gv.y + bv.y);
  o.z = f2bf((v.z - mu) * rstd * gv.z + bv.z);
  o.w = f2bf((v.w - mu) * rstd * gv.w + bv.w);
  *(u16x4*)(out + (size_t)row * DMODEL + tid * 4) = o;
}

// ---------------- fp32 [R][C] -> bf16 [C][R] ----------------
__global__ __launch_bounds__(256) void transpose_cast(const float* __restrict__ in,
                                                      u16* __restrict__ out, int R, int C) {
  __shared__ u16 tile[32][33];
  int c0 = blockIdx.x * 32, r0 = blockIdx.y * 32;
  int tx = threadIdx.x & 31, grp = threadIdx.x >> 5;
#pragma unroll
  for (int i = 0; i < 4; i++) {
    int r = grp * 4 + i;
    tile[r][tx] = f2bf(in[(size_t)(r0 + r) * C + c0 + tx]);
  }
  __syncthreads();
#pragma unroll
  for (int i = 0; i < 4; i++) {
    int rr = grp * 4 + i;
    out[(size_t)(c0 + rr) * R + r0 + tx] = tile[tx][rr];
  }
}

// ---------------- V slice of qkv -> Vt[bh][dh][s] ----------------
__global__ __launch_bounds__(256) void transpose_v(const u16* __restrict__ qkv,
                                                   u16* __restrict__ vt) {
  __shared__ u16 tile[32][33];
  int bh = blockIdx.z;
  int b = bh >> 4;
  int s0 = blockIdx.x * 32, d0 = blockIdx.y * 32;
  int h = bh & 15;
  int tx = threadIdx.x & 31, grp = threadIdx.x >> 5;
#pragma unroll
  for (int i = 0; i < 4; i++) {
    int sl = grp * 4 + i;
    tile[sl][tx] = qkv[(size_t)((s0 + sl) * BATCH + b) * 3072 + 2048 + h * DHEAD + d0 + tx];
  }
  __syncthreads();
#pragma unroll
  for (int i = 0; i < 4; i++) {
    int dl = grp * 4 + i;
    vt[((size_t)bh * DHEAD + d0 + dl) * S_LEN + s0 + tx] = tile[tx][dl];
  }
}

// ---------------- GEMM v3: BK=64, XOR-swizzled LDS, counted-vmcnt 2-phase pipeline ----
// C[M][N] = A[M][K](bf16) @ Bt[N][K](bf16)^T.  BM=128, BN in {128,64}.
// T4: prefetch loads stay in flight across barriers; s_waitcnt vmcnt(NLOADS) waits only
// for the PREVIOUS tile's loads (never drains to 0 in the main loop).
// MODE 0: bf16 out.  MODE 1: fp32 out = acc + res.
// MODE 2: bf16 out = relu(acc + bias).  MODE 3: fp32 out = acc + bias + res.
template <int MODE, int BN>
__global__ __launch_bounds__(256) void gemm_bt(const u16* __restrict__ A,
                                               const u16* __restrict__ Bt, void* __restrict__ Cout,
                                               const float* __restrict__ bias,
                                               const float* __restrict__ res, int M, int N, int K) {
  __shared__ __align__(16) u16 As[2][128 * 64];
  __shared__ __align__(16) u16 Bs[2][BN * 64];
  constexpr int NLOADS = 4 + BN / 32;  // gload_lds issued per wave per stage

  // XCD-chunked bijective block swizzle (grids here are all %8==0)
  int nwg = gridDim.x * gridDim.y;
  int f = blockIdx.y * gridDim.x + blockIdx.x;
  int nf = ((nwg & 7) == 0) ? ((f & 7) * (nwg >> 3) + (f >> 3)) : f;
  int bx = nf % gridDim.x, by = nf / gridDim.x;

  int bm0 = by * 128, bn0 = bx * BN;
  int tid = threadIdx.x, w = tid >> 6, lane = tid & 63;
  int g = lane >> 4, l15 = lane & 15;
  int lr = lane >> 3, ch = lane & 7;
  int srcch = (ch ^ lr) * 8;  // pre-swizzled 16B-chunk column offset (elements)
  int wm = (w >> 1) * 64, wn = (w & 1) * (BN / 2);
  const int NJ = BN / 32;  // wave n-frags per k-step

  f32x4 acc[4][NJ];
#pragma unroll
  for (int i = 0; i < 4; i++)
#pragma unroll
    for (int j = 0; j < NJ; j++) {
      f32x4 z = {0.f, 0.f, 0.f, 0.f};
      acc[i][j] = z;
    }

  auto stage = [&](int k0, int buf) {
#pragma unroll
    for (int rd = 0; rd < 4; rd++) {
      int rb = (rd * 4 + w) * 8;  // row base; this lane's row = rb + lr, row&7 == lr
      gload_lds16(A + (size_t)(bm0 + rb + lr) * K + k0 + srcch, &As[buf][rb * 64]);
    }
#pragma unroll
    for (int rd = 0; rd < BN / 32; rd++) {
      int rb = (rd * 4 + w) * 8;
      gload_lds16(Bt + (size_t)(bn0 + rb + lr) * K + k0 + srcch, &Bs[buf][rb * 64]);
    }
  };

  int nkt = K >> 6;
  stage(0, 0);
  asm volatile("s_waitcnt vmcnt(0)" ::: "memory");
  __builtin_amdgcn_s_barrier();

  for (int kt = 0; kt < nkt; ++kt) {
    int cur = kt & 1;
    if (kt + 1 < nkt) {
      stage((kt + 1) << 6, cur ^ 1);  // prefetch: stays in flight across the barrier
      asm volatile("s_waitcnt vmcnt(%0)" ::"n"(NLOADS) : "memory");  // cur's loads done
    } else {
      asm volatile("s_waitcnt vmcnt(0)" ::: "memory");
    }
    __builtin_amdgcn_s_barrier();  // all waves: cur buffer fully staged
#pragma unroll
    for (int kk = 0; kk < 2; kk++) {
      bf16x8 af[4], bfr[NJ];
#pragma unroll
      for (int i = 0; i < 4; i++) {
        int row = wm + i * 16 + l15;
        af[i] = *(const bf16x8*)&As[cur][row * 64 + (((kk * 4 + g) ^ (row & 7)) * 8)];
      }
#pragma unroll
      for (int j = 0; j < NJ; j++) {
        int row = wn + j * 16 + l15;
        bfr[j] = *(const bf16x8*)&Bs[cur][row * 64 + (((kk * 4 + g) ^ (row & 7)) * 8)];
      }
#pragma unroll
      for (int i = 0; i < 4; i++)
#pragma unroll
        for (int j = 0; j < NJ; j++) acc[i][j] = mfma16(af[i], bfr[j], acc[i][j]);
    }
    __builtin_amdgcn_s_barrier();  // all reads of cur done before next stage overwrites
  }

  // epilogue: D layout col = lane&15, row = 4*(lane>>4) + r
#pragma unroll
  for (int i = 0; i < 4; i++)
#pragma unroll
    for (int j = 0; j < NJ; j++) {
      int col = bn0 + wn + j * 16 + l15;
      float bval = (MODE == 2 || MODE == 3) ? bias[col] : 0.f;
#pragma unroll
      for (int r = 0; r < 4; r++) {
        int row = bm0 + wm + i * 16 + g * 4 + r;
        size_t idx = (size_t)row * N + col;
        float vacc = acc[i][j][r] + bval;
        if (MODE == 0)
          ((u16*)Cout)[idx] = f2bf(vacc);
        else if (MODE == 1)
          ((float*)Cout)[idx] = vacc + res[idx];
        else if (MODE == 2)
          ((u16*)Cout)[idx] = f2bf(fmaxf(vacc, 0.f));
        else
          ((float*)Cout)[idx] = vacc + res[idx];
      }
    }
}

// ---------------- flash attention v4 ----------------
// grid (S/64, B*H) XCD-chunked, 256 thr = 4 waves; wave owns 16 q rows.
// Swapped mfma(K,Q): lane holds S^T[t][q=l15]; softmax lane-local (raw-score domain,
// scale folded into exp2 FMA; defer-max THR skips alpha-rescale on most iters).
// P -> PV B-frag in-register (cvt_pk + permlane32/16 swaps). Counted-vmcnt prefetch.
__global__ __launch_bounds__(256) void attn_kernel(const u16* __restrict__ qkv,
                                                   const u16* __restrict__ vt,
                                                   u16* __restrict__ ctx) {
  int nwg = gridDim.x * gridDim.y;  // 1024
  int f = blockIdx.y * gridDim.x + blockIdx.x;
  int nf = (f & 7) * (nwg >> 3) + (f >> 3);  // XCD-chunked: each XCD gets 4 consecutive bh
  int qblk = nf % gridDim.x, bh = nf / gridDim.x;
  int b = bh >> 4, h = bh & 15;
  int tid = threadIdx.x, w = tid >> 6, lane = tid & 63;
  int g = lane >> 4, l15 = lane & 15;
  int lr = lane >> 3, ch = lane & 7;
  int q0 = qblk * 64 + w * 16;
  const float SCALE = 0.125f * 1.44269504f;  // 1/sqrt(64) * log2(e): exp2 domain
  const float RAW_THR = 44.0f;               // ~= 8 / SCALE (defer-max threshold)

  __shared__ __align__(16) u16 ks[2][64 * 64];
  __shared__ __align__(16) u16 vs[2][64 * 64];

  bf16x8 qf0, qf1;
  {
    const u16* qp = qkv + ((size_t)(q0 + l15) * BATCH + b) * 3072 + h * DHEAD;
    qf0 = *(const bf16x8*)(qp + g * 8);
    qf1 = *(const bf16x8*)(qp + 32 + g * 8);
  }

  f32x4 accT[4];  // [n]: col=q=l15, row=dh=n*16+4g+r
#pragma unroll
  for (int n = 0; n < 4; n++) {
    f32x4 z = {0.f, 0.f, 0.f, 0.f};
    accT[n] = z;
  }
  float mrun = -1e30f, lrun = 0.f;

  auto stage = [&](int t0, int buf) {
#pragma unroll
    for (int rd = 0; rd < 2; rd++) {
      int rb = w * 16 + rd * 8;
      int row = rb + lr;  // row & 7 == lr
      const u16* ksrc =
          qkv + ((size_t)(t0 + row) * BATCH + b) * 3072 + 1024 + h * DHEAD + (ch ^ lr) * 8;
      gload_lds16(ksrc, &ks[buf][rb * 64]);
      const u16* vsrc = vt + ((size_t)bh * DHEAD + row) * S_LEN + t0 + (ch ^ lr) * 8;
      gload_lds16(vsrc, &vs[buf][rb * 64]);
    }
  };

  stage(0, 0);
  asm volatile("s_waitcnt vmcnt(0)" ::: "memory");
  __builtin_amdgcn_s_barrier();

  for (int it = 0; it < S_LEN / 64; ++it) {
    int cur = it & 1;
    if (it + 1 < S_LEN / 64) {
      stage((it + 1) * 64, cur ^ 1);
      asm volatile("s_waitcnt vmcnt(4)" ::: "memory");  // cur's 4 loads landed
    } else {
      asm volatile("s_waitcnt vmcnt(0)" ::: "memory");
    }
    __builtin_amdgcn_s_barrier();

    // ---- QK^T (swapped): scT[tt][r] = S_raw^T[16tt+4g+r][q0+l15] ----
    f32x4 scT[4];
#pragma unroll
    for (int tt = 0; tt < 4; tt++) {
      int row = tt * 16 + l15;
      bf16x8 kf0 = *(const bf16x8*)&ks[cur][row * 64 + ((g ^ (row & 7)) * 8)];
      bf16x8 kf1 = *(const bf16x8*)&ks[cur][row * 64 + (((4 + g) ^ (row & 7)) * 8)];
      f32x4 z = {0.f, 0.f, 0.f, 0.f};
      __builtin_amdgcn_s_setprio(1);
      z = mfma16(kf0, qf0, z);
      z = mfma16(kf1, qf1, z);
      __builtin_amdgcn_s_setprio(0);
      scT[tt] = z;  // raw scores (scale folded into exp2 below)
    }

    // ---- online softmax (raw domain, defer-max) ----
    float pm = fmaxf(fmaxf(scT[0][0], scT[0][1]), fmaxf(scT[0][2], scT[0][3]));
#pragma unroll
    for (int tt = 1; tt < 4; tt++)
      pm = fmaxf(pm, fmaxf(fmaxf(scT[tt][0], scT[tt][1]), fmaxf(scT[tt][2], scT[tt][3])));
    pm = fmaxf(pm, __shfl_xor(pm, 16));
    pm = fmaxf(pm, __shfl_xor(pm, 32));
    if (__any(pm > mrun + RAW_THR)) {  // rescale only when max grew materially
      float mn = fmaxf(mrun, pm);
      float al = __builtin_amdgcn_exp2f((mrun - mn) * SCALE);
      mrun = mn;
      lrun *= al;
#pragma unroll
      for (int n = 0; n < 4; n++) accT[n] *= al;
    }
    float mns = mrun * SCALE;
    float p[4][4];
    float psum = 0.f;
#pragma unroll
    for (int tt = 0; tt < 4; tt++)
#pragma unroll
      for (int r = 0; r < 4; r++) {
        p[tt][r] = __builtin_amdgcn_exp2f(fmaf(scT[tt][r], SCALE, -mns));
        psum += p[tt][r];
      }
    psum += __shfl_xor(psum, 16);
    psum += __shfl_xor(psum, 32);
    lrun += psum;

    // ---- in-register P repack: reg=(t5,t4,t1),lane=(t3,t2) -> reg=(t5,t2,t1) ----
    uint32_t P32[4][2];
#pragma unroll
    for (int tt = 0; tt < 4; tt++)
#pragma unroll
      for (int m = 0; m < 2; m++) P32[tt][m] = cvt_pk_bf16(p[tt][2 * m], p[tt][2 * m + 1]);
#pragma unroll
    for (int t5 = 0; t5 < 2; t5++)
#pragma unroll
      for (int m = 0; m < 2; m++) {
        asm("v_permlane32_swap_b32 %0, %1" : "+v"(P32[2 * t5][m]), "+v"(P32[2 * t5 + 1][m]));
        asm("v_permlane16_swap_b32 %0, %1" : "+v"(P32[2 * t5][m]), "+v"(P32[2 * t5 + 1][m]));
      }
    bf16x8 pb[2];
#pragma unroll
    for (int s2 = 0; s2 < 2; s2++) {
      union { uint32_t u[4]; bf16x8 v; } uu;
      uu.u[0] = P32[2 * s2][0];
      uu.u[1] = P32[2 * s2][1];
      uu.u[2] = P32[2 * s2 + 1][0];
      uu.u[3] = P32[2 * s2 + 1][1];
      pb[s2] = uu.v;
    }

    // ---- PV (swapped): accT[n] += V^T-frag * P^T-frag ----
#pragma unroll
    for (int n = 0; n < 4; n++) {
      int vrow = n * 16 + l15;
      bf16x8 vf0 = *(const bf16x8*)&vs[cur][vrow * 64 + ((g ^ (vrow & 7)) * 8)];
      bf16x8 vf1 = *(const bf16x8*)&vs[cur][vrow * 64 + (((4 + g) ^ (vrow & 7)) * 8)];
      __builtin_amdgcn_s_setprio(1);
      accT[n] = mfma16(vf0, pb[0], accT[n]);
      accT[n] = mfma16(vf1, pb[1], accT[n]);
      __builtin_amdgcn_s_setprio(0);
    }
    __builtin_amdgcn_s_barrier();  // all reads of cur done before next stage overwrites
  }

  float inv = 1.f / lrun;
  int srow = q0 + l15;
#pragma unroll
  for (int n = 0; n < 4; n++) {
    u16x4 o;
    o.x = f2bf(accT[n][0] * inv);
    o.y = f2bf(accT[n][1] * inv);
    o.z = f2bf(accT[n][2] * inv);
    o.w = f2bf(accT[n][3] * inv);
    *(u16x4*)(ctx + ((size_t)srow * BATCH + b) * DMODEL + h * DHEAD + n * 16 + 4 * g) = o;
  }
}

extern "C" void kernel_launch(void* const* d_in, const int* in_sizes, int n_in, void* d_out,
                              int out_size, void* d_ws, size_t ws_size, hipStream_t stream) {
  (void)in_sizes; (void)n_in; (void)out_size; (void)ws_size;
  const float* x    = (const float*)d_in[0];
  const float* wq   = (const float*)d_in[1];
  const float* wk   = (const float*)d_in[2];
  const float* wv   = (const float*)d_in[3];
  const float* wo   = (const float*)d_in[4];
  const float* ln1g = (const float*)d_in[5];
  const float* ln1b = (const float*)d_in[6];
  const float* ln2g = (const float*)d_in[7];
  const float* ln2b = (const float*)d_in[8];
  const float* w1   = (const float*)d_in[9];
  const float* b1   = (const float*)d_in[10];
  const float* w2   = (const float*)d_in[11];
  const float* b2   = (const float*)d_in[12];

  char* ws = (char*)d_ws;
  size_t off = 0;
  auto alloc = [&](size_t bytes) {
    void* p = ws + off;
    off += (bytes + 255) & ~(size_t)255;
    return p;
  };
  u16* yb    = (u16*)alloc((size_t)MROWS * DMODEL * 2);
  u16* wqkvt = (u16*)alloc((size_t)3072 * 1024 * 2);
  u16* wot   = (u16*)alloc((size_t)1024 * 1024 * 2);
  u16* w1t   = (u16*)alloc((size_t)4096 * 1024 * 2);
  u16* w2t   = (u16*)alloc((size_t)1024 * 4096 * 2);
  u16* qkvb  = (u16*)alloc((size_t)MROWS * 3072 * 2);
  u16* vtb   = (u16*)alloc((size_t)BATCH * NHEAD * DHEAD * S_LEN * 2);
  u16* ctxb  = (u16*)alloc((size_t)MROWS * DMODEL * 2);
  float* x1  = (float*)alloc((size_t)MROWS * DMODEL * 4);
  u16* zb    = (u16*)alloc((size_t)MROWS * DMODEL * 2);
  u16* hb    = (u16*)alloc((size_t)MROWS * FFDIM * 2);

  // sublayer 0
  ln_kernel<<<MROWS, 256, 0, stream>>>(x, ln1g, ln1b, yb);
  transpose_cast<<<dim3(32, 32), 256, 0, stream>>>(wq, wqkvt, 1024, 1024);
  transpose_cast<<<dim3(32, 32), 256, 0, stream>>>(wk, wqkvt + 1024 * 1024, 1024, 1024);
  transpose_cast<<<dim3(32, 32), 256, 0, stream>>>(wv, wqkvt + 2 * 1024 * 1024, 1024, 1024);
  transpose_cast<<<dim3(32, 32), 256, 0, stream>>>(wo, wot, 1024, 1024);
  transpose_cast<<<dim3(128, 32), 256, 0, stream>>>(w1, w1t, 1024, 4096);
  transpose_cast<<<dim3(32, 128), 256, 0, stream>>>(w2, w2t, 4096, 1024);

  gemm_bt<0, 128><<<dim3(3072 / 128, 4096 / 128), 256, 0, stream>>>(yb, wqkvt, qkvb, nullptr,
                                                                    nullptr, 4096, 3072, 1024);
  transpose_v<<<dim3(64, 2, 32), 256, 0, stream>>>(qkvb, vtb);
  attn_kernel<<<dim3(32, 32), 256, 0, stream>>>(qkvb, vtb, ctxb);
  gemm_bt<1, 64><<<dim3(16, 32), 256, 0, stream>>>(ctxb, wot, x1, nullptr, x, 4096, 1024, 1024);

  // sublayer 1
  ln_kernel<<<MROWS, 256, 0, stream>>>(x1, ln2g, ln2b, zb);
  gemm_bt<2, 128><<<dim3(32, 32), 256, 0, stream>>>(zb, w1t, hb, b1, nullptr, 4096, 4096, 1024);
  gemm_bt<3, 64><<<dim3(16, 32), 256, 0, stream>>>(hb, w2t, d_out, b2, x1, 4096, 1024, 4096);
}